// Round 8
// baseline (420.694 us; speedup 1.0000x reference)
//
#include <hip/hip_runtime.h>
#include <hip/hip_bf16.h>
#include <math.h>
#include <stdint.h>

#define B_ 2
#define S_ 2048
#define E_ 2048
#define H_ 16
#define NOPE_ 64
#define ROPE_ 32
#define V_ 64
#define KVR_ 256
#define QKD_ 96
#define SCALE_ 0.10206207261596577f  /* 96^-0.5 */

typedef __hip_bfloat16 bf16;
typedef __attribute__((ext_vector_type(8))) short short8;
typedef __attribute__((ext_vector_type(4))) short short4v;
typedef __attribute__((ext_vector_type(4))) float floatx4;

__device__ __forceinline__ float bf2f(bf16 v) { return __bfloat162float(v); }
__device__ __forceinline__ float s2f(short v) {
    bf16 h = *reinterpret_cast<bf16*>(&v);
    return __bfloat162float(h);
}
__device__ __forceinline__ short f2bf_s(float f) {
    bf16 h = __float2bfloat16(f);
    return *reinterpret_cast<short*>(&h);
}
__device__ __forceinline__ void store_c(float* C, size_t i, float v) { C[i] = v; }
__device__ __forceinline__ void store_c(bf16* C, size_t i, float v) { C[i] = __float2bfloat16(v); }

// async 16B global -> LDS. Proper addrspacecasts (NO integer truncation — flat LDS
// addresses are aperture-based; C-style cast emits the correct addrspacecast).
__device__ __forceinline__ void g2l16(const bf16* g, bf16* l) {
    __builtin_amdgcn_global_load_lds(
        (const __attribute__((address_space(1))) void*)g,
        (__attribute__((address_space(3))) void*)l,
        16, 0, 0);
}

// ---------------- fused fp32 -> bf16 conversions + wkvbT transpose -----------------------
#define CV_N0 1048576              /* hs:    4096*2048/8 */
#define CV_N1 (CV_N0 + 393216)     /* wq:    1536*2048/8 */
#define CV_N2 (CV_N1 + 262144)     /* wo:    2048*1024/8 */
#define CV_N3 (CV_N2 + 65536)      /* wkv_b: 2048*256/8  */
#define CV_N4 (CV_N3 + 98304)      /* wkva_pad: 384*2048/8 */
#define CV_N5 (CV_N4 + 32768)      /* wkvbT: 16h x 8 d0-chunks x 256 c */
__global__ __launch_bounds__(256) void conv_fused_kernel(const float* __restrict__ hs,
                                                         const float* __restrict__ wq,
                                                         const float* __restrict__ wo,
                                                         const float* __restrict__ wkv_b,
                                                         const float* __restrict__ wkv_a,
                                                         bf16* __restrict__ hs_bf,
                                                         bf16* __restrict__ wq_bf,
                                                         bf16* __restrict__ wo_bf,
                                                         bf16* __restrict__ wkvb_bf,
                                                         bf16* __restrict__ wkva_pad,
                                                         bf16* __restrict__ wkvbT) {
    int i = blockIdx.x * 256 + threadIdx.x;
    const float* src;
    bf16* dst;
    int j;
    if (i < CV_N0)      { src = hs;    dst = hs_bf;   j = i; }
    else if (i < CV_N1) { src = wq;    dst = wq_bf;   j = i - CV_N0; }
    else if (i < CV_N2) { src = wo;    dst = wo_bf;   j = i - CV_N1; }
    else if (i < CV_N3) { src = wkv_b; dst = wkvb_bf; j = i - CV_N2; }
    else if (i < CV_N4) {
        j = i - CV_N3;
        int row = j >> 8;
        short8 r;
        if (row < 288) {
            float4 a = ((const float4*)wkv_a)[2 * j];
            float4 b = ((const float4*)wkv_a)[2 * j + 1];
            r[0] = f2bf_s(a.x); r[1] = f2bf_s(a.y); r[2] = f2bf_s(a.z); r[3] = f2bf_s(a.w);
            r[4] = f2bf_s(b.x); r[5] = f2bf_s(b.y); r[6] = f2bf_s(b.z); r[7] = f2bf_s(b.w);
        } else {
            for (int k = 0; k < 8; ++k) r[k] = 0;
        }
        ((short8*)wkva_pad)[j] = r;
        return;
    } else if (i < CV_N5) {
        j = i - CV_N4;
        int h = j >> 11;
        int rem = j & 2047;
        int d0 = (rem >> 8) * 8;
        int c = rem & 255;
        short8 v;
#pragma unroll
        for (int jj = 0; jj < 8; ++jj)
            v[jj] = f2bf_s(wkv_b[(size_t)(h * 128 + d0 + jj) * 256 + c]);
        *(short8*)(void*)&wkvbT[((size_t)h * 256 + c) * 64 + d0] = v;
        return;
    } else return;
    float4 a = ((const float4*)src)[2 * j];
    float4 b = ((const float4*)src)[2 * j + 1];
    short8 r;
    r[0] = f2bf_s(a.x); r[1] = f2bf_s(a.y); r[2] = f2bf_s(a.z); r[3] = f2bf_s(a.w);
    r[4] = f2bf_s(b.x); r[5] = f2bf_s(b.y); r[6] = f2bf_s(b.z); r[7] = f2bf_s(b.w);
    ((short8*)dst)[j] = r;
}

// ---------------- bf16 MFMA GEMM (m97-style): C(M,N) = A(M,K) @ B(N,K)^T ----------------
template <typename TC>
__global__ __launch_bounds__(256, 2) void gemm_bt_lds(const bf16* __restrict__ A,
                                                      const bf16* __restrict__ Bm,
                                                      TC* __restrict__ C,
                                                      int M, int N, int K) {
    __shared__ bf16 Asf[128 * 32];
    __shared__ bf16 Bsf[128 * 32];
    int tid = threadIdx.x;
    int lane = tid & 63, w = tid >> 6;
    int q4 = lane >> 4, c16 = lane & 15;
    int wr = w >> 1, wc = w & 1;
    int m0 = blockIdx.y * 128, n0 = blockIdx.x * 128;
    floatx4 acc[4][4];
#pragma unroll
    for (int mi = 0; mi < 4; ++mi)
#pragma unroll
        for (int ni = 0; ni < 4; ++ni) acc[mi][ni] = (floatx4){0.f, 0.f, 0.f, 0.f};

    for (int k0 = 0; k0 < K; k0 += 32) {
        __syncthreads();
#pragma unroll
        for (int i = 0; i < 2; ++i) {
            int c = (w << 6) + lane + i * 256;
            int row = c >> 2, kc = c & 3;
            g2l16(&A[(size_t)(m0 + row) * K + k0 + kc * 8], &Asf[c * 8]);
            g2l16(&Bm[(size_t)(n0 + row) * K + k0 + kc * 8], &Bsf[c * 8]);
        }
        __syncthreads();
        short8 af[4], bfr[4];
#pragma unroll
        for (int mi = 0; mi < 4; ++mi)
            af[mi] = *(const short8*)(const void*)&Asf[(wr * 64 + mi * 16 + c16) * 32 + q4 * 8];
#pragma unroll
        for (int ni = 0; ni < 4; ++ni)
            bfr[ni] = *(const short8*)(const void*)&Bsf[(wc * 64 + ni * 16 + c16) * 32 + q4 * 8];
#pragma unroll
        for (int mi = 0; mi < 4; ++mi)
#pragma unroll
            for (int ni = 0; ni < 4; ++ni)
                acc[mi][ni] = __builtin_amdgcn_mfma_f32_16x16x32_bf16(af[mi], bfr[ni], acc[mi][ni], 0, 0, 0);
    }
#pragma unroll
    for (int mi = 0; mi < 4; ++mi)
#pragma unroll
        for (int ni = 0; ni < 4; ++ni)
#pragma unroll
            for (int r = 0; r < 4; ++r) {
                int row = m0 + wr * 64 + mi * 16 + q4 * 4 + r;
                int col = n0 + wc * 64 + ni * 16 + c16;
                store_c(C, (size_t)row * N + col, acc[mi][ni][r]);
            }
}

// ---------------- fused projection GEMM, 64x128 tiles: q (bf16, N=1536) + kvraw (f32) ----
__global__ __launch_bounds__(256) void gemm_qkv_fused64(const bf16* __restrict__ A,
                                                        const bf16* __restrict__ Bq,
                                                        const bf16* __restrict__ Bkv,
                                                        bf16* __restrict__ Cq,
                                                        float* __restrict__ Ckv,
                                                        int K) {
    int bid = blockIdx.x;
    int orig = (bid & 7) * 120 + (bid >> 3);  // XCD-chunked: each XCD gets 120 consecutive
    int by = orig / 15, bx = orig % 15;
    bool isq = bx < 12;
    const bf16* Bm = isq ? Bq : Bkv;
    int n0 = isq ? bx * 128 : (bx - 12) * 128;
    int m0 = by * 64;
    __shared__ bf16 Asf[64 * 32];
    __shared__ bf16 Bsf[128 * 32];
    int tid = threadIdx.x;
    int lane = tid & 63, w = tid >> 6;
    int q4 = lane >> 4, c16 = lane & 15;
    int wr = w >> 1, wc = w & 1;  // wave covers rows wr*32..+32, cols wc*64..+64
    floatx4 acc[2][4];
#pragma unroll
    for (int mi = 0; mi < 2; ++mi)
#pragma unroll
        for (int ni = 0; ni < 4; ++ni) acc[mi][ni] = (floatx4){0.f, 0.f, 0.f, 0.f};

    for (int k0 = 0; k0 < K; k0 += 32) {
        __syncthreads();
        {
            int c = tid;  // A: 256 chunks, 1/thread
            int row = c >> 2, kc = c & 3;
            g2l16(&A[(size_t)(m0 + row) * K + k0 + kc * 8], &Asf[c * 8]);
        }
#pragma unroll
        for (int i = 0; i < 2; ++i) {  // B: 512 chunks, 2/thread
            int c = tid + i * 256;
            int row = c >> 2, kc = c & 3;
            g2l16(&Bm[(size_t)(n0 + row) * K + k0 + kc * 8], &Bsf[c * 8]);
        }
        __syncthreads();
        short8 af[2], bfr[4];
#pragma unroll
        for (int mi = 0; mi < 2; ++mi)
            af[mi] = *(const short8*)(const void*)&Asf[(wr * 32 + mi * 16 + c16) * 32 + q4 * 8];
#pragma unroll
        for (int ni = 0; ni < 4; ++ni)
            bfr[ni] = *(const short8*)(const void*)&Bsf[(wc * 64 + ni * 16 + c16) * 32 + q4 * 8];
#pragma unroll
        for (int mi = 0; mi < 2; ++mi)
#pragma unroll
            for (int ni = 0; ni < 4; ++ni)
                acc[mi][ni] = __builtin_amdgcn_mfma_f32_16x16x32_bf16(af[mi], bfr[ni], acc[mi][ni], 0, 0, 0);
    }
#pragma unroll
    for (int mi = 0; mi < 2; ++mi)
#pragma unroll
        for (int ni = 0; ni < 4; ++ni)
#pragma unroll
            for (int r = 0; r < 4; ++r) {
                int row = m0 + wr * 32 + mi * 16 + q4 * 4 + r;
                int col = n0 + wc * 64 + ni * 16 + c16;
                if (isq)
                    Cq[(size_t)row * 1536 + col] = __float2bfloat16(acc[mi][ni][r]);
                else
                    Ckv[(size_t)row * 384 + col] = acc[mi][ni][r];
            }
}

// ---------------- small batched bf16 MFMA GEMM (64x64 tiles, global_load_lds) -------------
template <typename TC>
__global__ __launch_bounds__(256, 4) void gemm64_lds(const bf16* __restrict__ A, int lda, int aoffz,
                                                     const bf16* __restrict__ Bm, int ldb, int boffz,
                                                     TC* __restrict__ C, int ldc, int coffz,
                                                     int K, float scale) {
    int z = blockIdx.z;
    A += (size_t)z * aoffz;
    Bm += (size_t)z * boffz;
    C += (size_t)z * coffz;
    __shared__ bf16 Asf[64 * 32];
    __shared__ bf16 Bsf[64 * 32];
    int tid = threadIdx.x;
    int lane = tid & 63, w = tid >> 6;
    int q4 = lane >> 4, c16 = lane & 15;
    int m0 = blockIdx.y * 64, n0 = blockIdx.x * 64;
    floatx4 acc[4];
#pragma unroll
    for (int ni = 0; ni < 4; ++ni) acc[ni] = (floatx4){0.f, 0.f, 0.f, 0.f};
    int row = tid >> 2, kc = tid & 3;
    for (int k0 = 0; k0 < K; k0 += 32) {
        __syncthreads();
        g2l16(&A[(size_t)(m0 + row) * lda + k0 + kc * 8], &Asf[tid * 8]);
        g2l16(&Bm[(size_t)(n0 + row) * ldb + k0 + kc * 8], &Bsf[tid * 8]);
        __syncthreads();
        short8 af = *(const short8*)(const void*)&Asf[(w * 16 + c16) * 32 + q4 * 8];
#pragma unroll
        for (int ni = 0; ni < 4; ++ni) {
            short8 bfr = *(const short8*)(const void*)&Bsf[(ni * 16 + c16) * 32 + q4 * 8];
            acc[ni] = __builtin_amdgcn_mfma_f32_16x16x32_bf16(af, bfr, acc[ni], 0, 0, 0);
        }
    }
#pragma unroll
    for (int ni = 0; ni < 4; ++ni)
#pragma unroll
        for (int rr = 0; rr < 4; ++rr)
            store_c(C, (size_t)(m0 + w * 16 + q4 * 4 + rr) * ldc + n0 + ni * 16 + c16,
                    acc[ni][rr] * scale);
}

// ---------------- fused C2/P2 + gates: writes g0/g1 only ----------------
__global__ __launch_bounds__(64) void c2p2g_kernel(const float* __restrict__ fcw_c,
                                                   const float* __restrict__ fcb_c,
                                                   const float* __restrict__ fcw_p,
                                                   const float* __restrict__ fcb_p,
                                                   float* __restrict__ g0,
                                                   float* __restrict__ g1) {
    int t = blockIdx.x;
    int k = threadIdx.x;
    __shared__ float Crow[256], Prow[256], Pprev[256];
    for (int i = k; i < 128; i += 64) {
        float div = expf(-(float)i * 0.07195578415606393f);  // ln(1e4)/128
        float ap = (float)t * div;
        Prow[2 * i]     = sinf(ap);
        Prow[2 * i + 1] = cosf(ap);
        float ac = (float)(t >> 1) * div;
        Crow[2 * i]     = sinf(ac);
        Crow[2 * i + 1] = cosf(ac);
        float app = (float)(t - 1) * div;  // unused for even t
        Pprev[2 * i]     = sinf(app);
        Pprev[2 * i + 1] = cosf(app);
    }
    __syncthreads();
    float sc = fcb_c[k], sp = fcb_p[k], spp = fcb_p[k];
    for (int c = 0; c < 256; ++c) {
        float wc_ = fcw_c[(size_t)k * 256 + c];
        float wp_ = fcw_p[(size_t)k * 256 + c];
        sc += Crow[c] * wc_;
        sp += Prow[c] * wp_;
        spp += Pprev[c] * wp_;
    }
    float d0 = sc * sp, d1 = sc * spp;
#pragma unroll
    for (int o = 32; o; o >>= 1) {
        d0 += __shfl_down(d0, o);
        d1 += __shfl_down(d1, o);
    }
    if (k == 0) {
        g0[t] = 1.0f / (1.0f + expf(-d0));
        g1[t] = (t & 1) ? 1.0f / (1.0f + expf(-d1)) : 0.f;
    }
}

// ---------------- fused LayerNorm + RoPE + gated kve (odd/even pair per block) -----------
__global__ __launch_bounds__(256) void lnkve_kernel(const float* __restrict__ kvraw,
                                                    const float* __restrict__ g,
                                                    const float* __restrict__ bta,
                                                    const float* __restrict__ g0,
                                                    const float* __restrict__ g1,
                                                    bf16* __restrict__ kve_full,
                                                    bf16* __restrict__ kvo) {
    int pb = blockIdx.x;
    int b = pb >> 10, u = pb & 1023;
    int t0 = 2 * u, t1 = 2 * u + 1;
    size_t r0 = (size_t)b * S_ + t0, r1 = r0 + 1;
    int tid = threadIdx.x;
    int lane = tid & 63, w = tid >> 6;
    float x0 = kvraw[r0 * 384 + tid];
    float x1 = kvraw[r1 * 384 + tid];
    float s0 = x0, q0 = x0 * x0, s1 = x1, q1 = x1 * x1;
#pragma unroll
    for (int o = 32; o; o >>= 1) {
        s0 += __shfl_down(s0, o); q0 += __shfl_down(q0, o);
        s1 += __shfl_down(s1, o); q1 += __shfl_down(q1, o);
    }
    __shared__ float red[4][4];
    __shared__ float st[4];
    if (lane == 0) { red[w][0] = s0; red[w][1] = q0; red[w][2] = s1; red[w][3] = q1; }
    __syncthreads();
    if (tid == 0) {
        float S0 = red[0][0] + red[1][0] + red[2][0] + red[3][0];
        float Q0 = red[0][1] + red[1][1] + red[2][1] + red[3][1];
        float S1 = red[0][2] + red[1][2] + red[2][2] + red[3][2];
        float Q1 = red[0][3] + red[1][3] + red[2][3] + red[3][3];
        float m0 = S0 / 256.0f, m1 = S1 / 256.0f;
        st[0] = m0; st[1] = rsqrtf(Q0 / 256.0f - m0 * m0 + 1e-5f);
        st[2] = m1; st[3] = rsqrtf(Q1 / 256.0f - m1 * m1 + 1e-5f);
    }
    __syncthreads();
    float gg = g[tid], bb_ = bta[tid];
    float y0 = (x0 - st[0]) * st[1] * gg + bb_;
    float y1 = (x1 - st[2]) * st[3] * gg + bb_;
    float a0 = g0[t0], a1 = g0[t1], b1 = g1[t1];
    kve_full[r0 * 288 + tid] = __float2bfloat16(a0 * y0);
    float vo = a1 * y1 + b1 * y0;
    bf16 vob = __float2bfloat16(vo);
    kve_full[r1 * 288 + tid] = vob;
    kvo[((size_t)b * 1024 + u) * 296 + tid] = vob;
    if (tid < 16) {
        int j = tid;
        float freq = expf(-(float)(2 * j) * 0.28782313662425572f);  // ln(1e4)/32
        float a00 = (float)t0 * freq, a01 = (float)t1 * freq;
        float c0 = cosf(a00), sn0 = sinf(a00);
        float c1 = cosf(a01), sn1 = sinf(a01);
        float e00 = kvraw[r0 * 384 + 256 + 2 * j], e01 = kvraw[r0 * 384 + 256 + 2 * j + 1];
        float e10 = kvraw[r1 * 384 + 256 + 2 * j], e11 = kvraw[r1 * 384 + 256 + 2 * j + 1];
        float k00 = e00 * c0 - e01 * sn0, k01 = e00 * sn0 + e01 * c0;
        float k10 = e10 * c1 - e11 * sn1, k11 = e10 * sn1 + e11 * c1;
        kve_full[r0 * 288 + 256 + 2 * j]     = __float2bfloat16(a0 * k00);
        kve_full[r0 * 288 + 256 + 2 * j + 1] = __float2bfloat16(a0 * k01);
        float u0 = a1 * k10 + b1 * k00, u1 = a1 * k11 + b1 * k01;
        bf16 u0b = __float2bfloat16(u0), u1b = __float2bfloat16(u1);
        kve_full[r1 * 288 + 256 + 2 * j]     = u0b;
        kve_full[r1 * 288 + 256 + 2 * j + 1] = u1b;
        kvo[((size_t)b * 1024 + u) * 296 + 256 + 2 * j]     = u0b;
        kvo[((size_t)b * 1024 + u) * 296 + 256 + 2 * j + 1] = u1b;
    }
}

// ---------------- kvoT32[b][uch][c][chunk] = kvo[b][uch*32 + tau(kslot)][c] --------------
// tau(8q+j) = (j<4) ? 4q+j : 16 + 4q + (j-4): aligns the score C-layout register order
// with the 16x16x32 PV A-operand k-slots. (XOR swizzle removed: attn now reads kvoT
// directly from global — no LDS banks involved; tau layout is naturally coalesced.)
__global__ __launch_bounds__(256) void kvoT32_kernel(const bf16* __restrict__ kvo,
                                                     bf16* __restrict__ kvoT) {
    int uch = blockIdx.x, b = blockIdx.y;
    int c = threadIdx.x;
    const bf16* src = kvo + ((size_t)b * 1024 + uch * 32) * 296 + c;
    short v[32];
#pragma unroll
    for (int j = 0; j < 32; ++j) v[j] = *(const short*)&src[(size_t)j * 296];
    bf16* dst = kvoT + (((size_t)b * 32 + uch) * 256 + c) * 32;
#pragma unroll
    for (int q = 0; q < 4; ++q) {
        short8 o;
#pragma unroll
        for (int jj = 0; jj < 8; ++jj)
            o[jj] = (jj < 4) ? v[4 * q + jj] : v[16 + 4 * q + (jj - 4)];
        *(short8*)(void*)&dst[q * 8] = o;
    }
}

// ---------------- roped, scaled q_pe -> qe[...,256:288) ----------------
__global__ __launch_bounds__(256) void rope_qe_kernel(const bf16* __restrict__ q,
                                                      bf16* __restrict__ qe) {
    int idx = blockIdx.x * 256 + threadIdx.x;
    if (idx >= B_ * S_ * H_ * 16) return;
    int j = idx & 15;
    int s = (idx >> 8) & (S_ - 1);
    float freq = expf(-(float)(2 * j) * 0.28782313662425572f);
    float ang = (float)s * freq;
    float c = cosf(ang), sn = sinf(ang);
    size_t row = idx >> 4;
    float a0 = bf2f(q[row * QKD_ + NOPE_ + 2 * j]);
    float a1 = bf2f(q[row * QKD_ + NOPE_ + 2 * j + 1]);
    qe[row * 288 + 256 + 2 * j]     = __float2bfloat16((a0 * c - a1 * sn) * SCALE_);
    qe[row * 288 + 256 + 2 * j + 1] = __float2bfloat16((a0 * sn + a1 * c) * SCALE_);
}

// ---------------- flash attention v9: NO LDS, NO barriers, 1 wave per block --------------
// kvo+kvoT (4.3 MB) are L2-resident; LDS staging was a pure extra copy (Common-mistake
// #7). Each wave streams K/V rows directly from global with the identical per-lane byte
// indexing the LDS reads had. Grid = (S, B) 64-thread blocks, biggest-first; each wave
// runs only its OWN niter (no NoddMax padding). Occupancy is VGPR-bound -> far more
// latency-hiding TLP than the 73KB-LDS version.
__global__ __launch_bounds__(64) void attn9_kernel(const bf16* __restrict__ qe,
                                                   const bf16* __restrict__ kvo,
                                                   const bf16* __restrict__ kvoT,
                                                   const bf16* __restrict__ kve_full,
                                                   bf16* __restrict__ xout) {
    int s = (int)(gridDim.x - 1 - blockIdx.x);  // biggest first
    int b = blockIdx.y;
    int lane = threadIdx.x & 63;
    int q4 = lane >> 4, c16 = lane & 15;
    int Nodd = (s + 1) >> 1;
    int niter = (Nodd + 31) >> 5;

    const bf16* kvob = kvo + (size_t)b * 1024 * 296;
    const bf16* kvoTb = kvoT + (size_t)b * 32 * 8192;
    const bf16* kverow = kve_full + (size_t)(b * S_ + s) * 288;

    short8 qf[9];
    const bf16* qrow = qe + ((size_t)(b * S_ + s) * H_ + c16) * 288;
#pragma unroll
    for (int kk = 0; kk < 9; ++kk) qf[kk] = *(const short8*)(const void*)&qrow[kk * 32 + q4 * 8];

    // self score: dot(qe_row(s,h=c16), kve_row(s)); reduce over q4 groups via shfl.
    float sdot = 0.f;
#pragma unroll
    for (int kk = 0; kk < 9; ++kk) {
        short8 kv8 = *(const short8*)(const void*)&kverow[kk * 32 + q4 * 8];
#pragma unroll
        for (int j = 0; j < 8; ++j) sdot += s2f(qf[kk][j]) * s2f(kv8[j]);
    }
    sdot += __shfl_xor(sdot, 16);
    sdot += __shfl_xor(sdot, 32);

    floatx4 acc[16];
#pragma unroll
    for (int n = 0; n < 16; ++n) acc[n] = (floatx4){0.f, 0.f, 0.f, 0.f};
    float m_i = -1e30f, l_i = 0.f;

    for (int it = 0; it < niter; ++it) {
        int u0 = it * 32;
        // scores^T for 32 keys: rows direct from L2. Lane reads K[u0+c16] (tile A) and
        // K[u0+16+c16] (tile B), 16B at kk*32+q4*8 — same bytes the LDS reads delivered.
        const bf16* ka = kvob + (size_t)(u0 + c16) * 296;
        const bf16* kb = kvob + (size_t)(u0 + 16 + c16) * 296;
        floatx4 ca0 = (floatx4){0.f, 0.f, 0.f, 0.f}, ca1 = (floatx4){0.f, 0.f, 0.f, 0.f};
        floatx4 cb0 = (floatx4){0.f, 0.f, 0.f, 0.f}, cb1 = (floatx4){0.f, 0.f, 0.f, 0.f};
        __builtin_amdgcn_s_setprio(1);
#pragma unroll
        for (int kk = 0; kk < 9; ++kk) {
            short8 avA = *(const short8*)(const void*)&ka[kk * 32 + q4 * 8];
            short8 avB = *(const short8*)(const void*)&kb[kk * 32 + q4 * 8];
            if (kk & 1) {
                ca1 = __builtin_amdgcn_mfma_f32_16x16x32_bf16(avA, qf[kk], ca1, 0, 0, 0);
                cb1 = __builtin_amdgcn_mfma_f32_16x16x32_bf16(avB, qf[kk], cb1, 0, 0, 0);
            } else {
                ca0 = __builtin_amdgcn_mfma_f32_16x16x32_bf16(avA, qf[kk], ca0, 0, 0, 0);
                cb0 = __builtin_amdgcn_mfma_f32_16x16x32_bf16(avB, qf[kk], cb0, 0, 0, 0);
            }
        }
        __builtin_amdgcn_s_setprio(0);
        floatx4 cA = ca0 + ca1;
        floatx4 cB = cb0 + cb1;
        int kA = u0 + q4 * 4;
        int kB = u0 + 16 + q4 * 4;
#pragma unroll
        for (int r = 0; r < 4; ++r) {
            if (kA + r >= Nodd) cA[r] = -1e30f;
            if (kB + r >= Nodd) cB[r] = -1e30f;
        }
        float tmax = fmaxf(fmaxf(fmaxf(cA[0], cA[1]), fmaxf(cA[2], cA[3])),
                           fmaxf(fmaxf(cB[0], cB[1]), fmaxf(cB[2], cB[3])));
        tmax = fmaxf(tmax, __shfl_xor(tmax, 16));
        tmax = fmaxf(tmax, __shfl_xor(tmax, 32));
        float mn = fmaxf(m_i, tmax);
        bool chg = mn > m_i;
        float al = __expf(m_i - mn);
        float pA0 = __expf(cA[0] - mn), pA1 = __expf(cA[1] - mn);
        float pA2 = __expf(cA[2] - mn), pA3 = __expf(cA[3] - mn);
        float pB0 = __expf(cB[0] - mn), pB1 = __expf(cB[1] - mn);
        float pB2 = __expf(cB[2] - mn), pB3 = __expf(cB[3] - mn);
        float rs = (pA0 + pA1 + pA2 + pA3) + (pB0 + pB1 + pB2 + pB3);
        rs += __shfl_xor(rs, 16);
        rs += __shfl_xor(rs, 32);
        l_i = l_i * al + rs;
        m_i = mn;
        if (__any(chg)) {
#pragma unroll
            for (int n = 0; n < 16; ++n) {
                acc[n][0] *= al; acc[n][1] *= al; acc[n][2] *= al; acc[n][3] *= al;
            }
        }
        // PV: A-operand row (n*16+c16) of the tau-ordered V tile, direct from L2.
        // For fixed n the 64 lanes cover 16 consecutive 64B rows -> 1KB contiguous.
        short8 pf;
        pf[0] = f2bf_s(pA0); pf[1] = f2bf_s(pA1); pf[2] = f2bf_s(pA2); pf[3] = f2bf_s(pA3);
        pf[4] = f2bf_s(pB0); pf[5] = f2bf_s(pB1); pf[6] = f2bf_s(pB2); pf[7] = f2bf_s(pB3);
        const bf16* vt = kvoTb + (size_t)it * 8192;
        __builtin_amdgcn_s_setprio(1);
#pragma unroll
        for (int n = 0; n < 16; ++n) {
            short8 a8 = *(const short8*)(const void*)&vt[(size_t)(n * 16 + c16) * 32 + q4 * 8];
            acc[n] = __builtin_amdgcn_mfma_f32_16x16x32_bf16(a8, pf, acc[n], 0, 0, 0);
        }
        __builtin_amdgcn_s_setprio(0);
    }

    // self key (even s; odd s already included in the odd set)
    if ((s & 1) == 0) {
        float mn = fmaxf(m_i, sdot);
        float al = __expf(m_i - mn);
        float pp = __expf(sdot - mn);
        l_i = l_i * al + pp;
        m_i = mn;
#pragma unroll
        for (int n = 0; n < 16; ++n) {
            short4v kv4 = *(const short4v*)(const void*)&kverow[n * 16 + q4 * 4];
#pragma unroll
            for (int r = 0; r < 4; ++r)
                acc[n][r] = acc[n][r] * al + pp * s2f(kv4[r]);
        }
    }

    float invl = 1.0f / l_i;
    bf16* orow = xout + ((size_t)(b * S_ + s) * H_ + c16) * 256;
#pragma unroll
    for (int n = 0; n < 16; ++n) {
        short4v o;
        o[0] = f2bf_s(acc[n][0] * invl);
        o[1] = f2bf_s(acc[n][1] * invl);
        o[2] = f2bf_s(acc[n][2] * invl);
        o[3] = f2bf_s(acc[n][3] * invl);
        *(short4v*)(void*)&orow[n * 16 + q4 * 4] = o;
    }
}

extern "C" void kernel_launch(void* const* d_in, const int* in_sizes, int n_in,
                              void* d_out, int out_size, void* d_ws, size_t ws_size,
                              hipStream_t stream) {
    const float* hs     = (const float*)d_in[0];
    const float* wq     = (const float*)d_in[1];
    const float* wkv_a  = (const float*)d_in[2];
    const float* ln_g   = (const float*)d_in[3];
    const float* ln_b   = (const float*)d_in[4];
    const float* wkv_b  = (const float*)d_in[5];
    const float* wo     = (const float*)d_in[6];
    const float* fc_c_w = (const float*)d_in[7];
    const float* fc_c_b = (const float*)d_in[8];
    const float* fc_p_w = (const float*)d_in[9];
    const float* fc_p_b = (const float*)d_in[10];
    float* out = (float*)d_out;
    (void)in_sizes; (void)n_in; (void)out_size; (void)ws_size;

    const int M = B_ * S_;  // 4096
    char* wsb = (char*)d_ws;
    size_t o = 0;
    auto alloc = [&](size_t bytes) { char* p = wsb + o; o += (bytes + 255) & ~(size_t)255; return p; };

    bf16* qe = (bf16*)alloc((size_t)M * H_ * 288 * 2);  // 37.75 MB
    char* region2 = alloc((size_t)M * H_ * 256 * 2);    // 33.55 MB
    bf16* hs_bf    = (bf16*)region2;
    bf16* wq_bf    = (bf16*)(region2 + (size_t)M * E_ * 2);
    bf16* wkva_pad = (bf16*)(region2 + (size_t)M * E_ * 2 + (size_t)1536 * E_ * 2);
    bf16* x_bf     = (bf16*)region2;
    char* region3 = alloc((size_t)M * 1536 * 2);        // 12.58 MB
    bf16* q_bf    = (bf16*)region3;
    bf16* outp_bf = (bf16*)region3;
    float* kvraw = (float*)alloc((size_t)M * 384 * 4);
    bf16* wo_bf   = (bf16*)alloc((size_t)E_ * 1024 * 2);
    bf16* wkvb_bf = (bf16*)alloc((size_t)2048 * 256 * 2);
    bf16* wkvbT   = (bf16*)alloc((size_t)H_ * 256 * 64 * 2);
    bf16* kve_full = (bf16*)alloc((size_t)M * 288 * 2);
    bf16* kvo      = (bf16*)alloc((size_t)B_ * 1024 * 296 * 2);
    bf16* kvoT     = (bf16*)alloc((size_t)B_ * 32 * 8192 * 2);
    float* g0 = (float*)alloc(S_ * 4);
    float* g1 = (float*)alloc(S_ * 4);

    // fused conversions + wkvbT transpose — one launch
    conv_fused_kernel<<<(CV_N5 + 255) / 256, 256, 0, stream>>>(
        hs, wq, wo, wkv_b, wkv_a, hs_bf, wq_bf, wo_bf, wkvb_bf, wkva_pad, wkvbT);
    // fused projections: q (bf16) + kvraw (f32), 64x128 tiles, 960 blocks, XCD swizzle
    gemm_qkv_fused64<<<960, 256, 0, stream>>>(hs_bf, wq_bf, wkva_pad, q_bf, kvraw, E_);
    // gates (C2/P2 fused in)
    c2p2g_kernel<<<S_, 64, 0, stream>>>(fc_c_w, fc_c_b, fc_p_w, fc_p_b, g0, g1);
    // LN + rope + gated kve (pair-block)
    lnkve_kernel<<<B_ * 1024, 256, 0, stream>>>(kvraw, ln_g, ln_b, g0, g1, kve_full, kvo);
    kvoT32_kernel<<<dim3(32, B_), 256, 0, stream>>>(kvo, kvoT);
    // qe = [q_abs * SCALE | rope(q_pe) * SCALE]
    gemm64_lds<bf16><<<dim3(256 / 64, M / 64, H_), 256, 0, stream>>>(
        q_bf, H_ * QKD_, QKD_, wkvbT, 64, 256 * 64, qe, H_ * 288, 288, 64, SCALE_);
    rope_qe_kernel<<<(M * H_ * 16 + 255) / 256, 256, 0, stream>>>(q_bf, qe);
    // attention v9: LDS-free, barrier-free, 1 wave/block, direct L2 streams
    attn9_kernel<<<dim3(S_, B_), 64, 0, stream>>>(qe, kvo, kvoT, kve_full, x_bf);
    // V-projection per head
    gemm64_lds<bf16><<<dim3(1, M / 64, H_), 256, 0, stream>>>(
        x_bf, H_ * 256, 256, wkvb_bf + (size_t)64 * 256, 256, 128 * 256, outp_bf, 1024, 64, 256, 1.0f);
    // final out = outp @ wo^T
    gemm_bt_lds<float><<<dim3(E_ / 128, M / 128), 256, 0, stream>>>(outp_bf, wo_bf, out, M, E_, 1024);
}

// Round 9
// 335.795 us; speedup vs baseline: 1.2528x; 1.2528x over previous
//
#include <hip/hip_runtime.h>
#include <hip/hip_bf16.h>
#include <math.h>
#include <stdint.h>

#define B_ 2
#define S_ 2048
#define E_ 2048
#define H_ 16
#define NOPE_ 64
#define ROPE_ 32
#define V_ 64
#define KVR_ 256
#define QKD_ 96
#define SCALE_ 0.10206207261596577f  /* 96^-0.5 */

typedef __hip_bfloat16 bf16;
typedef __attribute__((ext_vector_type(8))) short short8;
typedef __attribute__((ext_vector_type(4))) short short4v;
typedef __attribute__((ext_vector_type(4))) float floatx4;

__device__ __forceinline__ float bf2f(bf16 v) { return __bfloat162float(v); }
__device__ __forceinline__ float s2f(short v) {
    bf16 h = *reinterpret_cast<bf16*>(&v);
    return __bfloat162float(h);
}
__device__ __forceinline__ short f2bf_s(float f) {
    bf16 h = __float2bfloat16(f);
    return *reinterpret_cast<short*>(&h);
}
__device__ __forceinline__ void store_c(float* C, size_t i, float v) { C[i] = v; }
__device__ __forceinline__ void store_c(bf16* C, size_t i, float v) { C[i] = __float2bfloat16(v); }

// async 16B global -> LDS. Proper addrspacecasts (NO integer truncation — flat LDS
// addresses are aperture-based; C-style cast emits the correct addrspacecast).
__device__ __forceinline__ void g2l16(const bf16* g, bf16* l) {
    __builtin_amdgcn_global_load_lds(
        (const __attribute__((address_space(1))) void*)g,
        (__attribute__((address_space(3))) void*)l,
        16, 0, 0);
}

// ---------------- fused fp32 -> bf16 conversions + wkvbT transpose -----------------------
#define CV_N0 1048576              /* hs:    4096*2048/8 */
#define CV_N1 (CV_N0 + 393216)     /* wq:    1536*2048/8 */
#define CV_N2 (CV_N1 + 262144)     /* wo:    2048*1024/8 */
#define CV_N3 (CV_N2 + 65536)      /* wkv_b: 2048*256/8  */
#define CV_N4 (CV_N3 + 98304)      /* wkva_pad: 384*2048/8 */
#define CV_N5 (CV_N4 + 32768)      /* wkvbT: 16h x 8 d0-chunks x 256 c */
__global__ __launch_bounds__(256) void conv_fused_kernel(const float* __restrict__ hs,
                                                         const float* __restrict__ wq,
                                                         const float* __restrict__ wo,
                                                         const float* __restrict__ wkv_b,
                                                         const float* __restrict__ wkv_a,
                                                         bf16* __restrict__ hs_bf,
                                                         bf16* __restrict__ wq_bf,
                                                         bf16* __restrict__ wo_bf,
                                                         bf16* __restrict__ wkvb_bf,
                                                         bf16* __restrict__ wkva_pad,
                                                         bf16* __restrict__ wkvbT) {
    int i = blockIdx.x * 256 + threadIdx.x;
    const float* src;
    bf16* dst;
    int j;
    if (i < CV_N0)      { src = hs;    dst = hs_bf;   j = i; }
    else if (i < CV_N1) { src = wq;    dst = wq_bf;   j = i - CV_N0; }
    else if (i < CV_N2) { src = wo;    dst = wo_bf;   j = i - CV_N1; }
    else if (i < CV_N3) { src = wkv_b; dst = wkvb_bf; j = i - CV_N2; }
    else if (i < CV_N4) {
        j = i - CV_N3;
        int row = j >> 8;
        short8 r;
        if (row < 288) {
            float4 a = ((const float4*)wkv_a)[2 * j];
            float4 b = ((const float4*)wkv_a)[2 * j + 1];
            r[0] = f2bf_s(a.x); r[1] = f2bf_s(a.y); r[2] = f2bf_s(a.z); r[3] = f2bf_s(a.w);
            r[4] = f2bf_s(b.x); r[5] = f2bf_s(b.y); r[6] = f2bf_s(b.z); r[7] = f2bf_s(b.w);
        } else {
            for (int k = 0; k < 8; ++k) r[k] = 0;
        }
        ((short8*)wkva_pad)[j] = r;
        return;
    } else if (i < CV_N5) {
        j = i - CV_N4;
        int h = j >> 11;
        int rem = j & 2047;
        int d0 = (rem >> 8) * 8;
        int c = rem & 255;
        short8 v;
#pragma unroll
        for (int jj = 0; jj < 8; ++jj)
            v[jj] = f2bf_s(wkv_b[(size_t)(h * 128 + d0 + jj) * 256 + c]);
        *(short8*)(void*)&wkvbT[((size_t)h * 256 + c) * 64 + d0] = v;
        return;
    } else return;
    float4 a = ((const float4*)src)[2 * j];
    float4 b = ((const float4*)src)[2 * j + 1];
    short8 r;
    r[0] = f2bf_s(a.x); r[1] = f2bf_s(a.y); r[2] = f2bf_s(a.z); r[3] = f2bf_s(a.w);
    r[4] = f2bf_s(b.x); r[5] = f2bf_s(b.y); r[6] = f2bf_s(b.z); r[7] = f2bf_s(b.w);
    ((short8*)dst)[j] = r;
}

// ---------------- bf16 MFMA GEMM (m97-style): C(M,N) = A(M,K) @ B(N,K)^T ----------------
template <typename TC>
__global__ __launch_bounds__(256, 2) void gemm_bt_lds(const bf16* __restrict__ A,
                                                      const bf16* __restrict__ Bm,
                                                      TC* __restrict__ C,
                                                      int M, int N, int K) {
    __shared__ bf16 Asf[128 * 32];
    __shared__ bf16 Bsf[128 * 32];
    int tid = threadIdx.x;
    int lane = tid & 63, w = tid >> 6;
    int q4 = lane >> 4, c16 = lane & 15;
    int wr = w >> 1, wc = w & 1;
    int m0 = blockIdx.y * 128, n0 = blockIdx.x * 128;
    floatx4 acc[4][4];
#pragma unroll
    for (int mi = 0; mi < 4; ++mi)
#pragma unroll
        for (int ni = 0; ni < 4; ++ni) acc[mi][ni] = (floatx4){0.f, 0.f, 0.f, 0.f};

    for (int k0 = 0; k0 < K; k0 += 32) {
        __syncthreads();
#pragma unroll
        for (int i = 0; i < 2; ++i) {
            int c = (w << 6) + lane + i * 256;
            int row = c >> 2, kc = c & 3;
            g2l16(&A[(size_t)(m0 + row) * K + k0 + kc * 8], &Asf[c * 8]);
            g2l16(&Bm[(size_t)(n0 + row) * K + k0 + kc * 8], &Bsf[c * 8]);
        }
        __syncthreads();
        short8 af[4], bfr[4];
#pragma unroll
        for (int mi = 0; mi < 4; ++mi)
            af[mi] = *(const short8*)(const void*)&Asf[(wr * 64 + mi * 16 + c16) * 32 + q4 * 8];
#pragma unroll
        for (int ni = 0; ni < 4; ++ni)
            bfr[ni] = *(const short8*)(const void*)&Bsf[(wc * 64 + ni * 16 + c16) * 32 + q4 * 8];
#pragma unroll
        for (int mi = 0; mi < 4; ++mi)
#pragma unroll
            for (int ni = 0; ni < 4; ++ni)
                acc[mi][ni] = __builtin_amdgcn_mfma_f32_16x16x32_bf16(af[mi], bfr[ni], acc[mi][ni], 0, 0, 0);
    }
#pragma unroll
    for (int mi = 0; mi < 4; ++mi)
#pragma unroll
        for (int ni = 0; ni < 4; ++ni)
#pragma unroll
            for (int r = 0; r < 4; ++r) {
                int row = m0 + wr * 64 + mi * 16 + q4 * 4 + r;
                int col = n0 + wc * 64 + ni * 16 + c16;
                store_c(C, (size_t)row * N + col, acc[mi][ni][r]);
            }
}

// ---------------- fused projection GEMM, 64x128 tiles: q (bf16, N=1536) + kvraw (f32) ----
__global__ __launch_bounds__(256) void gemm_qkv_fused64(const bf16* __restrict__ A,
                                                        const bf16* __restrict__ Bq,
                                                        const bf16* __restrict__ Bkv,
                                                        bf16* __restrict__ Cq,
                                                        float* __restrict__ Ckv,
                                                        int K) {
    int bid = blockIdx.x;
    int orig = (bid & 7) * 120 + (bid >> 3);  // XCD-chunked: each XCD gets 120 consecutive
    int by = orig / 15, bx = orig % 15;
    bool isq = bx < 12;
    const bf16* Bm = isq ? Bq : Bkv;
    int n0 = isq ? bx * 128 : (bx - 12) * 128;
    int m0 = by * 64;
    __shared__ bf16 Asf[64 * 32];
    __shared__ bf16 Bsf[128 * 32];
    int tid = threadIdx.x;
    int lane = tid & 63, w = tid >> 6;
    int q4 = lane >> 4, c16 = lane & 15;
    int wr = w >> 1, wc = w & 1;  // wave covers rows wr*32..+32, cols wc*64..+64
    floatx4 acc[2][4];
#pragma unroll
    for (int mi = 0; mi < 2; ++mi)
#pragma unroll
        for (int ni = 0; ni < 4; ++ni) acc[mi][ni] = (floatx4){0.f, 0.f, 0.f, 0.f};

    for (int k0 = 0; k0 < K; k0 += 32) {
        __syncthreads();
        {
            int c = tid;  // A: 256 chunks, 1/thread
            int row = c >> 2, kc = c & 3;
            g2l16(&A[(size_t)(m0 + row) * K + k0 + kc * 8], &Asf[c * 8]);
        }
#pragma unroll
        for (int i = 0; i < 2; ++i) {  // B: 512 chunks, 2/thread
            int c = tid + i * 256;
            int row = c >> 2, kc = c & 3;
            g2l16(&Bm[(size_t)(n0 + row) * K + k0 + kc * 8], &Bsf[c * 8]);
        }
        __syncthreads();
        short8 af[2], bfr[4];
#pragma unroll
        for (int mi = 0; mi < 2; ++mi)
            af[mi] = *(const short8*)(const void*)&Asf[(wr * 32 + mi * 16 + c16) * 32 + q4 * 8];
#pragma unroll
        for (int ni = 0; ni < 4; ++ni)
            bfr[ni] = *(const short8*)(const void*)&Bsf[(wc * 64 + ni * 16 + c16) * 32 + q4 * 8];
#pragma unroll
        for (int mi = 0; mi < 2; ++mi)
#pragma unroll
            for (int ni = 0; ni < 4; ++ni)
                acc[mi][ni] = __builtin_amdgcn_mfma_f32_16x16x32_bf16(af[mi], bfr[ni], acc[mi][ni], 0, 0, 0);
    }
#pragma unroll
    for (int mi = 0; mi < 2; ++mi)
#pragma unroll
        for (int ni = 0; ni < 4; ++ni)
#pragma unroll
            for (int r = 0; r < 4; ++r) {
                int row = m0 + wr * 32 + mi * 16 + q4 * 4 + r;
                int col = n0 + wc * 64 + ni * 16 + c16;
                if (isq)
                    Cq[(size_t)row * 1536 + col] = __float2bfloat16(acc[mi][ni][r]);
                else
                    Ckv[(size_t)row * 384 + col] = acc[mi][ni][r];
            }
}

// ---------------- small batched bf16 MFMA GEMM (64x64 tiles, global_load_lds) -------------
template <typename TC>
__global__ __launch_bounds__(256, 4) void gemm64_lds(const bf16* __restrict__ A, int lda, int aoffz,
                                                     const bf16* __restrict__ Bm, int ldb, int boffz,
                                                     TC* __restrict__ C, int ldc, int coffz,
                                                     int K, float scale) {
    int z = blockIdx.z;
    A += (size_t)z * aoffz;
    Bm += (size_t)z * boffz;
    C += (size_t)z * coffz;
    __shared__ bf16 Asf[64 * 32];
    __shared__ bf16 Bsf[64 * 32];
    int tid = threadIdx.x;
    int lane = tid & 63, w = tid >> 6;
    int q4 = lane >> 4, c16 = lane & 15;
    int m0 = blockIdx.y * 64, n0 = blockIdx.x * 64;
    floatx4 acc[4];
#pragma unroll
    for (int ni = 0; ni < 4; ++ni) acc[ni] = (floatx4){0.f, 0.f, 0.f, 0.f};
    int row = tid >> 2, kc = tid & 3;
    for (int k0 = 0; k0 < K; k0 += 32) {
        __syncthreads();
        g2l16(&A[(size_t)(m0 + row) * lda + k0 + kc * 8], &Asf[tid * 8]);
        g2l16(&Bm[(size_t)(n0 + row) * ldb + k0 + kc * 8], &Bsf[tid * 8]);
        __syncthreads();
        short8 af = *(const short8*)(const void*)&Asf[(w * 16 + c16) * 32 + q4 * 8];
#pragma unroll
        for (int ni = 0; ni < 4; ++ni) {
            short8 bfr = *(const short8*)(const void*)&Bsf[(ni * 16 + c16) * 32 + q4 * 8];
            acc[ni] = __builtin_amdgcn_mfma_f32_16x16x32_bf16(af, bfr, acc[ni], 0, 0, 0);
        }
    }
#pragma unroll
    for (int ni = 0; ni < 4; ++ni)
#pragma unroll
        for (int rr = 0; rr < 4; ++rr)
            store_c(C, (size_t)(m0 + w * 16 + q4 * 4 + rr) * ldc + n0 + ni * 16 + c16,
                    acc[ni][rr] * scale);
}

// ---------------- qe GEMM specialized: K=64 in ONE phase (2 K-planes staged at once) -----
// Replaces the 2-K-step gemm64 path: one barrier pair instead of four+. LDS layout
// [plane][64][32] is LINEAR in the staging chunk index (global_load_lds-compatible) and
// keeps the proven BK=32 bank behavior. C = qe[...,0:256) scaled by SCALE_.
__global__ __launch_bounds__(256, 4) void gemm_qe_k64(const bf16* __restrict__ A,
                                                      const bf16* __restrict__ Bm,
                                                      bf16* __restrict__ C) {
    int z = blockIdx.z;
    A += (size_t)z * QKD_;
    Bm += (size_t)z * 256 * 64;
    C += (size_t)z * 288;
    __shared__ bf16 Asf[2][64][32];
    __shared__ bf16 Bsf[2][64][32];
    int tid = threadIdx.x;
    int lane = tid & 63, w = tid >> 6;
    int q4 = lane >> 4, c16 = lane & 15;
    int m0 = blockIdx.y * 64, n0 = blockIdx.x * 64;
#pragma unroll
    for (int i = 0; i < 2; ++i) {
        int c = tid + i * 256;           // 512 chunks each; LDS addr = c*16B (linear)
        int pl = c >> 8, r = (c >> 2) & 63, kc = c & 3;
        g2l16(&A[(size_t)(m0 + r) * (H_ * QKD_) + pl * 32 + kc * 8], &Asf[pl][r][kc * 8]);
        g2l16(&Bm[(size_t)(n0 + r) * 64 + pl * 32 + kc * 8], &Bsf[pl][r][kc * 8]);
    }
    __syncthreads();
    floatx4 acc[4];
#pragma unroll
    for (int ni = 0; ni < 4; ++ni) acc[ni] = (floatx4){0.f, 0.f, 0.f, 0.f};
#pragma unroll
    for (int kk = 0; kk < 2; ++kk) {
        short8 af = *(const short8*)(const void*)&Asf[kk][w * 16 + c16][q4 * 8];
#pragma unroll
        for (int ni = 0; ni < 4; ++ni) {
            short8 bfr = *(const short8*)(const void*)&Bsf[kk][ni * 16 + c16][q4 * 8];
            acc[ni] = __builtin_amdgcn_mfma_f32_16x16x32_bf16(af, bfr, acc[ni], 0, 0, 0);
        }
    }
#pragma unroll
    for (int ni = 0; ni < 4; ++ni)
#pragma unroll
        for (int rr = 0; rr < 4; ++rr)
            C[(size_t)(m0 + w * 16 + q4 * 4 + rr) * (H_ * 288) + n0 + ni * 16 + c16] =
                __float2bfloat16(acc[ni][rr] * SCALE_);
}

// ---------------- fused C2/P2 + gates: writes g0/g1 only ----------------
__global__ __launch_bounds__(64) void c2p2g_kernel(const float* __restrict__ fcw_c,
                                                   const float* __restrict__ fcb_c,
                                                   const float* __restrict__ fcw_p,
                                                   const float* __restrict__ fcb_p,
                                                   float* __restrict__ g0,
                                                   float* __restrict__ g1) {
    int t = blockIdx.x;
    int k = threadIdx.x;
    __shared__ float Crow[256], Prow[256], Pprev[256];
    for (int i = k; i < 128; i += 64) {
        float div = expf(-(float)i * 0.07195578415606393f);  // ln(1e4)/128
        float ap = (float)t * div;
        Prow[2 * i]     = sinf(ap);
        Prow[2 * i + 1] = cosf(ap);
        float ac = (float)(t >> 1) * div;
        Crow[2 * i]     = sinf(ac);
        Crow[2 * i + 1] = cosf(ac);
        float app = (float)(t - 1) * div;  // unused for even t
        Pprev[2 * i]     = sinf(app);
        Pprev[2 * i + 1] = cosf(app);
    }
    __syncthreads();
    // float4 weight loads: this kernel is 1 wave/block, latency-bound on the serial
    // weight walk — quartering the load count shortens the dependency chain.
    float sc = fcb_c[k], sp = fcb_p[k], spp = fcb_p[k];
    const float4* wc4 = (const float4*)&fcw_c[(size_t)k * 256];
    const float4* wp4 = (const float4*)&fcw_p[(size_t)k * 256];
#pragma unroll 4
    for (int c4 = 0; c4 < 64; ++c4) {
        float4 wcv = wc4[c4];
        float4 wpv = wp4[c4];
        int c = c4 * 4;
        sc  += Crow[c] * wcv.x + Crow[c + 1] * wcv.y + Crow[c + 2] * wcv.z + Crow[c + 3] * wcv.w;
        sp  += Prow[c] * wpv.x + Prow[c + 1] * wpv.y + Prow[c + 2] * wpv.z + Prow[c + 3] * wpv.w;
        spp += Pprev[c] * wpv.x + Pprev[c + 1] * wpv.y + Pprev[c + 2] * wpv.z + Pprev[c + 3] * wpv.w;
    }
    float d0 = sc * sp, d1 = sc * spp;
#pragma unroll
    for (int o = 32; o; o >>= 1) {
        d0 += __shfl_down(d0, o);
        d1 += __shfl_down(d1, o);
    }
    if (k == 0) {
        g0[t] = 1.0f / (1.0f + expf(-d0));
        g1[t] = (t & 1) ? 1.0f / (1.0f + expf(-d1)) : 0.f;
    }
}

// ---------------- fused LayerNorm + RoPE + gated kve (odd/even pair per block) -----------
__global__ __launch_bounds__(256) void lnkve_kernel(const float* __restrict__ kvraw,
                                                    const float* __restrict__ g,
                                                    const float* __restrict__ bta,
                                                    const float* __restrict__ g0,
                                                    const float* __restrict__ g1,
                                                    bf16* __restrict__ kve_full,
                                                    bf16* __restrict__ kvo) {
    int pb = blockIdx.x;
    int b = pb >> 10, u = pb & 1023;
    int t0 = 2 * u, t1 = 2 * u + 1;
    size_t r0 = (size_t)b * S_ + t0, r1 = r0 + 1;
    int tid = threadIdx.x;
    int lane = tid & 63, w = tid >> 6;
    float x0 = kvraw[r0 * 384 + tid];
    float x1 = kvraw[r1 * 384 + tid];
    float s0 = x0, q0 = x0 * x0, s1 = x1, q1 = x1 * x1;
#pragma unroll
    for (int o = 32; o; o >>= 1) {
        s0 += __shfl_down(s0, o); q0 += __shfl_down(q0, o);
        s1 += __shfl_down(s1, o); q1 += __shfl_down(q1, o);
    }
    __shared__ float red[4][4];
    __shared__ float st[4];
    if (lane == 0) { red[w][0] = s0; red[w][1] = q0; red[w][2] = s1; red[w][3] = q1; }
    __syncthreads();
    if (tid == 0) {
        float S0 = red[0][0] + red[1][0] + red[2][0] + red[3][0];
        float Q0 = red[0][1] + red[1][1] + red[2][1] + red[3][1];
        float S1 = red[0][2] + red[1][2] + red[2][2] + red[3][2];
        float Q1 = red[0][3] + red[1][3] + red[2][3] + red[3][3];
        float m0 = S0 / 256.0f, m1 = S1 / 256.0f;
        st[0] = m0; st[1] = rsqrtf(Q0 / 256.0f - m0 * m0 + 1e-5f);
        st[2] = m1; st[3] = rsqrtf(Q1 / 256.0f - m1 * m1 + 1e-5f);
    }
    __syncthreads();
    float gg = g[tid], bb_ = bta[tid];
    float y0 = (x0 - st[0]) * st[1] * gg + bb_;
    float y1 = (x1 - st[2]) * st[3] * gg + bb_;
    float a0 = g0[t0], a1 = g0[t1], b1 = g1[t1];
    kve_full[r0 * 288 + tid] = __float2bfloat16(a0 * y0);
    float vo = a1 * y1 + b1 * y0;
    bf16 vob = __float2bfloat16(vo);
    kve_full[r1 * 288 + tid] = vob;
    kvo[((size_t)b * 1024 + u) * 296 + tid] = vob;
    if (tid < 16) {
        int j = tid;
        float freq = expf(-(float)(2 * j) * 0.28782313662425572f);  // ln(1e4)/32
        float a00 = (float)t0 * freq, a01 = (float)t1 * freq;
        float c0 = cosf(a00), sn0 = sinf(a00);
        float c1 = cosf(a01), sn1 = sinf(a01);
        float e00 = kvraw[r0 * 384 + 256 + 2 * j], e01 = kvraw[r0 * 384 + 256 + 2 * j + 1];
        float e10 = kvraw[r1 * 384 + 256 + 2 * j], e11 = kvraw[r1 * 384 + 256 + 2 * j + 1];
        float k00 = e00 * c0 - e01 * sn0, k01 = e00 * sn0 + e01 * c0;
        float k10 = e10 * c1 - e11 * sn1, k11 = e10 * sn1 + e11 * c1;
        kve_full[r0 * 288 + 256 + 2 * j]     = __float2bfloat16(a0 * k00);
        kve_full[r0 * 288 + 256 + 2 * j + 1] = __float2bfloat16(a0 * k01);
        float u0 = a1 * k10 + b1 * k00, u1 = a1 * k11 + b1 * k01;
        bf16 u0b = __float2bfloat16(u0), u1b = __float2bfloat16(u1);
        kve_full[r1 * 288 + 256 + 2 * j]     = u0b;
        kve_full[r1 * 288 + 256 + 2 * j + 1] = u1b;
        kvo[((size_t)b * 1024 + u) * 296 + 256 + 2 * j]     = u0b;
        kvo[((size_t)b * 1024 + u) * 296 + 256 + 2 * j + 1] = u1b;
    }
}

// ---------------- kvoT32[b][uch][c][chunk] = kvo[b][uch*32 + tau(kslot)][c] --------------
// tau(8q+j) = (j<4) ? 4q+j : 16 + 4q + (j-4); chunks XOR-swizzled (chunk^((c>>1)&3)) so
// linear global_load_lds staging lands conflict-free (HW-verified R4/R5).
__global__ __launch_bounds__(256) void kvoT32_kernel(const bf16* __restrict__ kvo,
                                                     bf16* __restrict__ kvoT) {
    int uch = blockIdx.x, b = blockIdx.y;
    int c = threadIdx.x;
    const bf16* src = kvo + ((size_t)b * 1024 + uch * 32) * 296 + c;
    short v[32];
#pragma unroll
    for (int j = 0; j < 32; ++j) v[j] = *(const short*)&src[(size_t)j * 296];
    bf16* dst = kvoT + (((size_t)b * 32 + uch) * 256 + c) * 32;
    int swz = (c >> 1) & 3;
#pragma unroll
    for (int q = 0; q < 4; ++q) {
        short8 o;
#pragma unroll
        for (int jj = 0; jj < 8; ++jj)
            o[jj] = (jj < 4) ? v[4 * q + jj] : v[16 + 4 * q + (jj - 4)];
        *(short8*)(void*)&dst[(q ^ swz) * 8] = o;
    }
}

// ---------------- roped, scaled q_pe -> qe[...,256:288) ----------------
__global__ __launch_bounds__(256) void rope_qe_kernel(const bf16* __restrict__ q,
                                                      bf16* __restrict__ qe) {
    int idx = blockIdx.x * 256 + threadIdx.x;
    if (idx >= B_ * S_ * H_ * 16) return;
    int j = idx & 15;
    int s = (idx >> 8) & (S_ - 1);
    float freq = expf(-(float)(2 * j) * 0.28782313662425572f);
    float ang = (float)s * freq;
    float c = cosf(ang), sn = sinf(ang);
    size_t row = idx >> 4;
    float a0 = bf2f(q[row * QKD_ + NOPE_ + 2 * j]);
    float a1 = bf2f(q[row * QKD_ + NOPE_ + 2 * j + 1]);
    qe[row * 288 + 256 + 2 * j]     = __float2bfloat16((a0 * c - a1 * sn) * SCALE_);
    qe[row * 288 + 256 + 2 * j + 1] = __float2bfloat16((a0 * sn + a1 * c) * SCALE_);
}

// ---------------- flash attention: 32-key tiles, dbuf, XOR-swizzled PV, fused sscore -----
// (R7 attn8 restored verbatim — best measured attn structure.)
__global__ __launch_bounds__(256, 2) void attn8_kernel(const bf16* __restrict__ qe,
                                                       const bf16* __restrict__ kvo,
                                                       const bf16* __restrict__ kvoT,
                                                       const bf16* __restrict__ kve_full,
                                                       bf16* __restrict__ xout) {
    int s0 = (int)(gridDim.x - 1 - blockIdx.x) * 4;  // biggest blocks first
    int b = blockIdx.y;
    int tid = threadIdx.x;
    int lane = tid & 63, w = tid >> 6;
    int q4 = lane >> 4, c16 = lane & 15;
    int s = s0 + w;
    int Nodd = (s + 1) >> 1;
    int NoddMax = (s0 + 4) >> 1;
    int niter = (NoddMax + 31) >> 5;

    __shared__ bf16 kvos[2][32][296];   // 2 x 18944 B: score-side K rows
    __shared__ bf16 kvts[2][256][32];   // 2 x 16384 B: PV-side V tile (tau+XOR layout)
    __shared__ bf16 selfr[4][288];      // self-key kv rows, FULL 288 channels

    const bf16* kvob = kvo + (size_t)b * 1024 * 296;
    const bf16* kvoTb = kvoT + (size_t)b * 32 * 8192;

    if (tid < 144) {
        int rr = tid / 36, ch = tid - rr * 36;
        *(short8*)(void*)&selfr[rr][ch * 8] =
            *(const short8*)(const void*)&kve_full[(size_t)(b * S_ + s0 + rr) * 288 + ch * 8];
    }

    short8 qf[9];
    const bf16* qrow = qe + ((size_t)(b * S_ + s) * H_ + c16) * 288;
#pragma unroll
    for (int kk = 0; kk < 9; ++kk) qf[kk] = *(const short8*)(const void*)&qrow[kk * 32 + q4 * 8];

    floatx4 acc[16];
#pragma unroll
    for (int n = 0; n < 16; ++n) acc[n] = (floatx4){0.f, 0.f, 0.f, 0.f};
    float m_i = -1e30f, l_i = 0.f;
    int swz = (c16 >> 1) & 3;  // PV chunk XOR (matches kvoT32 writer)

    auto stage = [&](int t, int p) {
        const bf16* sa = kvob + (size_t)t * 32 * 296;
        bf16* la = &kvos[p][0][0];
#pragma unroll
        for (int i = 0; i < 4; ++i)
            g2l16(&sa[(size_t)(tid + i * 256) * 8], &la[(size_t)(tid + i * 256) * 8]);
        if (tid < 160) g2l16(&sa[(size_t)(tid + 1024) * 8], &la[(size_t)(tid + 1024) * 8]);
        const bf16* sb = kvoTb + (size_t)t * 8192;
        bf16* lb = &kvts[p][0][0];
#pragma unroll
        for (int i = 0; i < 4; ++i)
            g2l16(&sb[(size_t)(tid + i * 256) * 8], &lb[(size_t)(tid + i * 256) * 8]);
    };

    stage(0, 0);
    __syncthreads();  // prologue drain (also makes selfr visible)

    // in-register self score: dot(qe_row(s,h=c16), kve_row(s)); reduce over q4 via shfl.
    float sdot = 0.f;
#pragma unroll
    for (int kk = 0; kk < 9; ++kk) {
        short8 kv8 = *(const short8*)(const void*)&selfr[w][kk * 32 + q4 * 8];
#pragma unroll
        for (int j = 0; j < 8; ++j) sdot += s2f(qf[kk][j]) * s2f(kv8[j]);
    }
    sdot += __shfl_xor(sdot, 16);
    sdot += __shfl_xor(sdot, 32);

    for (int it = 0; it < niter; ++it) {
        int p = it & 1;
        if (it + 1 < niter) stage(it + 1, 1 - p);

        int u0 = it * 32;
        floatx4 ca0 = (floatx4){0.f, 0.f, 0.f, 0.f}, ca1 = (floatx4){0.f, 0.f, 0.f, 0.f};
        floatx4 cb0 = (floatx4){0.f, 0.f, 0.f, 0.f}, cb1 = (floatx4){0.f, 0.f, 0.f, 0.f};
        __builtin_amdgcn_s_setprio(1);
#pragma unroll
        for (int kk = 0; kk < 9; ++kk) {
            short8 avA = *(const short8*)(const void*)&kvos[p][c16][kk * 32 + q4 * 8];
            short8 avB = *(const short8*)(const void*)&kvos[p][16 + c16][kk * 32 + q4 * 8];
            if (kk & 1) {
                ca1 = __builtin_amdgcn_mfma_f32_16x16x32_bf16(avA, qf[kk], ca1, 0, 0, 0);
                cb1 = __builtin_amdgcn_mfma_f32_16x16x32_bf16(avB, qf[kk], cb1, 0, 0, 0);
            } else {
                ca0 = __builtin_amdgcn_mfma_f32_16x16x32_bf16(avA, qf[kk], ca0, 0, 0, 0);
                cb0 = __builtin_amdgcn_mfma_f32_16x16x32_bf16(avB, qf[kk], cb0, 0, 0, 0);
            }
        }
        __builtin_amdgcn_s_setprio(0);
        floatx4 cA = ca0 + ca1;
        floatx4 cB = cb0 + cb1;
        int kA = u0 + q4 * 4;
        int kB = u0 + 16 + q4 * 4;
#pragma unroll
        for (int r = 0; r < 4; ++r) {
            if (kA + r >= Nodd) cA[r] = -1e30f;
            if (kB + r >= Nodd) cB[r] = -1e30f;
        }
        float tmax = fmaxf(fmaxf(fmaxf(cA[0], cA[1]), fmaxf(cA[2], cA[3])),
                           fmaxf(fmaxf(cB[0], cB[1]), fmaxf(cB[2], cB[3])));
        tmax = fmaxf(tmax, __shfl_xor(tmax, 16));
        tmax = fmaxf(tmax, __shfl_xor(tmax, 32));
        float mn = fmaxf(m_i, tmax);
        bool chg = mn > m_i;
        float al = __expf(m_i - mn);
        float pA0 = __expf(cA[0] - mn), pA1 = __expf(cA[1] - mn);
        float pA2 = __expf(cA[2] - mn), pA3 = __expf(cA[3] - mn);
        float pB0 = __expf(cB[0] - mn), pB1 = __expf(cB[1] - mn);
        float pB2 = __expf(cB[2] - mn), pB3 = __expf(cB[3] - mn);
        float rs = (pA0 + pA1 + pA2 + pA3) + (pB0 + pB1 + pB2 + pB3);
        rs += __shfl_xor(rs, 16);
        rs += __shfl_xor(rs, 32);
        l_i = l_i * al + rs;
        m_i = mn;
        if (__any(chg)) {
#pragma unroll
            for (int n = 0; n < 16; ++n) {
                acc[n][0] *= al; acc[n][1] *= al; acc[n][2] *= al; acc[n][3] *= al;
            }
        }
        short8 pf;
        pf[0] = f2bf_s(pA0); pf[1] = f2bf_s(pA1); pf[2] = f2bf_s(pA2); pf[3] = f2bf_s(pA3);
        pf[4] = f2bf_s(pB0); pf[5] = f2bf_s(pB1); pf[6] = f2bf_s(pB2); pf[7] = f2bf_s(pB3);
        __builtin_amdgcn_s_setprio(1);
#pragma unroll
        for (int n = 0; n < 16; ++n) {
            short8 a8 = *(const short8*)(const void*)&kvts[p][n * 16 + c16][(q4 ^ swz) * 8];
            acc[n] = __builtin_amdgcn_mfma_f32_16x16x32_bf16(a8, pf, acc[n], 0, 0, 0);
        }
        __builtin_amdgcn_s_setprio(0);
        __syncthreads();
    }

    if ((s & 1) == 0) {
        float mn = fmaxf(m_i, sdot);
        float al = __expf(m_i - mn);
        float pp = __expf(sdot - mn);
        l_i = l_i * al + pp;
        m_i = mn;
#pragma unroll
        for (int n = 0; n < 16; ++n) {
            short4v kv4 = *(const short4v*)(const void*)&selfr[w][n * 16 + q4 * 4];
#pragma unroll
            for (int r = 0; r < 4; ++r)
                acc[n][r] = acc[n][r] * al + pp * s2f(kv4[r]);
        }
    }

    float invl = 1.0f / l_i;
    bf16* orow = xout + ((size_t)(b * S_ + s) * H_ + c16) * 256;
#pragma unroll
    for (int n = 0; n < 16; ++n) {
        short4v o;
        o[0] = f2bf_s(acc[n][0] * invl);
        o[1] = f2bf_s(acc[n][1] * invl);
        o[2] = f2bf_s(acc[n][2] * invl);
        o[3] = f2bf_s(acc[n][3] * invl);
        *(short4v*)(void*)&orow[n * 16 + q4 * 4] = o;
    }
}

extern "C" void kernel_launch(void* const* d_in, const int* in_sizes, int n_in,
                              void* d_out, int out_size, void* d_ws, size_t ws_size,
                              hipStream_t stream) {
    const float* hs     = (const float*)d_in[0];
    const float* wq     = (const float*)d_in[1];
    const float* wkv_a  = (const float*)d_in[2];
    const float* ln_g   = (const float*)d_in[3];
    const float* ln_b   = (const float*)d_in[4];
    const float* wkv_b  = (const float*)d_in[5];
    const float* wo     = (const float*)d_in[6];
    const float* fc_c_w = (const float*)d_in[7];
    const float* fc_c_b = (const float*)d_in[8];
    const float* fc_p_w = (const float*)d_in[9];
    const float* fc_p_b = (const float*)d_in[10];
    float* out = (float*)d_out;
    (void)in_sizes; (void)n_in; (void)out_size; (void)ws_size;

    const int M = B_ * S_;  // 4096
    char* wsb = (char*)d_ws;
    size_t o = 0;
    auto alloc = [&](size_t bytes) { char* p = wsb + o; o += (bytes + 255) & ~(size_t)255; return p; };

    bf16* qe = (bf16*)alloc((size_t)M * H_ * 288 * 2);  // 37.75 MB
    char* region2 = alloc((size_t)M * H_ * 256 * 2);    // 33.55 MB
    bf16* hs_bf    = (bf16*)region2;
    bf16* wq_bf    = (bf16*)(region2 + (size_t)M * E_ * 2);
    bf16* wkva_pad = (bf16*)(region2 + (size_t)M * E_ * 2 + (size_t)1536 * E_ * 2);
    bf16* x_bf     = (bf16*)region2;
    char* region3 = alloc((size_t)M * 1536 * 2);        // 12.58 MB
    bf16* q_bf    = (bf16*)region3;
    bf16* outp_bf = (bf16*)region3;
    float* kvraw = (float*)alloc((size_t)M * 384 * 4);
    bf16* wo_bf   = (bf16*)alloc((size_t)E_ * 1024 * 2);
    bf16* wkvb_bf = (bf16*)alloc((size_t)2048 * 256 * 2);
    bf16* wkvbT   = (bf16*)alloc((size_t)H_ * 256 * 64 * 2);
    bf16* kve_full = (bf16*)alloc((size_t)M * 288 * 2);
    bf16* kvo      = (bf16*)alloc((size_t)B_ * 1024 * 296 * 2);
    bf16* kvoT     = (bf16*)alloc((size_t)B_ * 32 * 8192 * 2);
    float* g0 = (float*)alloc(S_ * 4);
    float* g1 = (float*)alloc(S_ * 4);

    // fused conversions + wkvbT transpose — one launch
    conv_fused_kernel<<<(CV_N5 + 255) / 256, 256, 0, stream>>>(
        hs, wq, wo, wkv_b, wkv_a, hs_bf, wq_bf, wo_bf, wkvb_bf, wkva_pad, wkvbT);
    // fused projections: q (bf16) + kvraw (f32), 64x128 tiles, 960 blocks, XCD swizzle
    gemm_qkv_fused64<<<960, 256, 0, stream>>>(hs_bf, wq_bf, wkva_pad, q_bf, kvraw, E_);
    // gates (C2/P2 fused in, float4 weight loads)
    c2p2g_kernel<<<S_, 64, 0, stream>>>(fc_c_w, fc_c_b, fc_p_w, fc_p_b, g0, g1);
    // LN + rope + gated kve (pair-block)
    lnkve_kernel<<<B_ * 1024, 256, 0, stream>>>(kvraw, ln_g, ln_b, g0, g1, kve_full, kvo);
    kvoT32_kernel<<<dim3(32, B_), 256, 0, stream>>>(kvo, kvoT);
    // qe = [q_abs * SCALE | rope(q_pe) * SCALE]  (single-phase K=64 GEMM)
    gemm_qe_k64<<<dim3(4, 64, 16), 256, 0, stream>>>(q_bf, wkvbT, qe);
    rope_qe_kernel<<<(M * H_ * 16 + 255) / 256, 256, 0, stream>>>(q_bf, qe);
    // attention (32-key tiles, dbuf, XOR-deconflicted PV, fused self-score) — R7 verbatim
    attn8_kernel<<<dim3(S_ / 4, B_), 256, 0, stream>>>(qe, kvo, kvoT, kve_full, x_bf);
    // V-projection per head
    gemm64_lds<bf16><<<dim3(1, M / 64, H_), 256, 0, stream>>>(
        x_bf, H_ * 256, 256, wkvb_bf + (size_t)64 * 256, 256, 128 * 256, outp_bf, 1024, 64, 256, 1.0f);
    // final out = outp @ wo^T
    gemm_bt_lds<float><<<dim3(E_ / 128, M / 128), 256, 0, stream>>>(outp_bf, wo_bf, out, M, E_, 1024);
}

// Round 10
// 331.577 us; speedup vs baseline: 1.2688x; 1.0127x over previous
//
#include <hip/hip_runtime.h>
#include <hip/hip_bf16.h>
#include <math.h>
#include <stdint.h>

#define B_ 2
#define S_ 2048
#define E_ 2048
#define H_ 16
#define NOPE_ 64
#define ROPE_ 32
#define V_ 64
#define KVR_ 256
#define QKD_ 96
#define SCALE_ 0.10206207261596577f  /* 96^-0.5 */

typedef __hip_bfloat16 bf16;
typedef __attribute__((ext_vector_type(8))) short short8;
typedef __attribute__((ext_vector_type(4))) short short4v;
typedef __attribute__((ext_vector_type(4))) float floatx4;

__device__ __forceinline__ float bf2f(bf16 v) { return __bfloat162float(v); }
__device__ __forceinline__ float s2f(short v) {
    bf16 h = *reinterpret_cast<bf16*>(&v);
    return __bfloat162float(h);
}
__device__ __forceinline__ short f2bf_s(float f) {
    bf16 h = __float2bfloat16(f);
    return *reinterpret_cast<short*>(&h);
}
__device__ __forceinline__ void store_c(float* C, size_t i, float v) { C[i] = v; }
__device__ __forceinline__ void store_c(bf16* C, size_t i, float v) { C[i] = __float2bfloat16(v); }

// async 16B global -> LDS. Proper addrspacecasts (NO integer truncation — flat LDS
// addresses are aperture-based; C-style cast emits the correct addrspacecast).
__device__ __forceinline__ void g2l16(const bf16* g, bf16* l) {
    __builtin_amdgcn_global_load_lds(
        (const __attribute__((address_space(1))) void*)g,
        (__attribute__((address_space(3))) void*)l,
        16, 0, 0);
}

// ---------------- fused fp32 -> bf16 conversions + wkvbT transpose -----------------------
#define CV_N0 1048576              /* hs:    4096*2048/8 */
#define CV_N1 (CV_N0 + 393216)     /* wq:    1536*2048/8 */
#define CV_N2 (CV_N1 + 262144)     /* wo:    2048*1024/8 */
#define CV_N3 (CV_N2 + 65536)      /* wkv_b: 2048*256/8  */
#define CV_N4 (CV_N3 + 98304)      /* wkva_pad: 384*2048/8 */
#define CV_N5 (CV_N4 + 32768)      /* wkvbT: 16h x 8 d0-chunks x 256 c */
__global__ __launch_bounds__(256) void conv_fused_kernel(const float* __restrict__ hs,
                                                         const float* __restrict__ wq,
                                                         const float* __restrict__ wo,
                                                         const float* __restrict__ wkv_b,
                                                         const float* __restrict__ wkv_a,
                                                         bf16* __restrict__ hs_bf,
                                                         bf16* __restrict__ wq_bf,
                                                         bf16* __restrict__ wo_bf,
                                                         bf16* __restrict__ wkvb_bf,
                                                         bf16* __restrict__ wkva_pad,
                                                         bf16* __restrict__ wkvbT) {
    int i = blockIdx.x * 256 + threadIdx.x;
    const float* src;
    bf16* dst;
    int j;
    if (i < CV_N0)      { src = hs;    dst = hs_bf;   j = i; }
    else if (i < CV_N1) { src = wq;    dst = wq_bf;   j = i - CV_N0; }
    else if (i < CV_N2) { src = wo;    dst = wo_bf;   j = i - CV_N1; }
    else if (i < CV_N3) { src = wkv_b; dst = wkvb_bf; j = i - CV_N2; }
    else if (i < CV_N4) {
        j = i - CV_N3;
        int row = j >> 8;
        short8 r;
        if (row < 288) {
            float4 a = ((const float4*)wkv_a)[2 * j];
            float4 b = ((const float4*)wkv_a)[2 * j + 1];
            r[0] = f2bf_s(a.x); r[1] = f2bf_s(a.y); r[2] = f2bf_s(a.z); r[3] = f2bf_s(a.w);
            r[4] = f2bf_s(b.x); r[5] = f2bf_s(b.y); r[6] = f2bf_s(b.z); r[7] = f2bf_s(b.w);
        } else {
            for (int k = 0; k < 8; ++k) r[k] = 0;
        }
        ((short8*)wkva_pad)[j] = r;
        return;
    } else if (i < CV_N5) {
        j = i - CV_N4;
        int h = j >> 11;
        int rem = j & 2047;
        int d0 = (rem >> 8) * 8;
        int c = rem & 255;
        short8 v;
#pragma unroll
        for (int jj = 0; jj < 8; ++jj)
            v[jj] = f2bf_s(wkv_b[(size_t)(h * 128 + d0 + jj) * 256 + c]);
        *(short8*)(void*)&wkvbT[((size_t)h * 256 + c) * 64 + d0] = v;
        return;
    } else return;
    float4 a = ((const float4*)src)[2 * j];
    float4 b = ((const float4*)src)[2 * j + 1];
    short8 r;
    r[0] = f2bf_s(a.x); r[1] = f2bf_s(a.y); r[2] = f2bf_s(a.z); r[3] = f2bf_s(a.w);
    r[4] = f2bf_s(b.x); r[5] = f2bf_s(b.y); r[6] = f2bf_s(b.z); r[7] = f2bf_s(b.w);
    ((short8*)dst)[j] = r;
}

// ---------------- bf16 MFMA GEMM (m97-style): C(M,N) = A(M,K) @ B(N,K)^T ----------------
template <typename TC>
__global__ __launch_bounds__(256, 2) void gemm_bt_lds(const bf16* __restrict__ A,
                                                      const bf16* __restrict__ Bm,
                                                      TC* __restrict__ C,
                                                      int M, int N, int K) {
    __shared__ bf16 Asf[128 * 32];
    __shared__ bf16 Bsf[128 * 32];
    int tid = threadIdx.x;
    int lane = tid & 63, w = tid >> 6;
    int q4 = lane >> 4, c16 = lane & 15;
    int wr = w >> 1, wc = w & 1;
    int m0 = blockIdx.y * 128, n0 = blockIdx.x * 128;
    floatx4 acc[4][4];
#pragma unroll
    for (int mi = 0; mi < 4; ++mi)
#pragma unroll
        for (int ni = 0; ni < 4; ++ni) acc[mi][ni] = (floatx4){0.f, 0.f, 0.f, 0.f};

    for (int k0 = 0; k0 < K; k0 += 32) {
        __syncthreads();
#pragma unroll
        for (int i = 0; i < 2; ++i) {
            int c = (w << 6) + lane + i * 256;
            int row = c >> 2, kc = c & 3;
            g2l16(&A[(size_t)(m0 + row) * K + k0 + kc * 8], &Asf[c * 8]);
            g2l16(&Bm[(size_t)(n0 + row) * K + k0 + kc * 8], &Bsf[c * 8]);
        }
        __syncthreads();
        short8 af[4], bfr[4];
#pragma unroll
    for (int mi = 0; mi < 4; ++mi)
            af[mi] = *(const short8*)(const void*)&Asf[(wr * 64 + mi * 16 + c16) * 32 + q4 * 8];
#pragma unroll
        for (int ni = 0; ni < 4; ++ni)
            bfr[ni] = *(const short8*)(const void*)&Bsf[(wc * 64 + ni * 16 + c16) * 32 + q4 * 8];
#pragma unroll
        for (int mi = 0; mi < 4; ++mi)
#pragma unroll
            for (int ni = 0; ni < 4; ++ni)
                acc[mi][ni] = __builtin_amdgcn_mfma_f32_16x16x32_bf16(af[mi], bfr[ni], acc[mi][ni], 0, 0, 0);
    }
#pragma unroll
    for (int mi = 0; mi < 4; ++mi)
#pragma unroll
        for (int ni = 0; ni < 4; ++ni)
#pragma unroll
            for (int r = 0; r < 4; ++r) {
                int row = m0 + wr * 64 + mi * 16 + q4 * 4 + r;
                int col = n0 + wc * 64 + ni * 16 + c16;
                store_c(C, (size_t)row * N + col, acc[mi][ni][r]);
            }
}

// ---------------- fused projection GEMM, 128x128 tiles: q (bf16, N=1536) + kvraw (f32) ---
// Back to the m97-proven 128^2 structure (64 FLOP per staged LDS byte vs the 64x128
// tile's 43.7 — the 64-tile variant was staging-bound). 1D grid of 480 blocks with a
// bijective XCD-chunked swizzle (480 % 8 == 0; 60 consecutive tiles per XCD).
__global__ __launch_bounds__(256, 2) void gemm_qkv_fused128(const bf16* __restrict__ A,
                                                            const bf16* __restrict__ Bq,
                                                            const bf16* __restrict__ Bkv,
                                                            bf16* __restrict__ Cq,
                                                            float* __restrict__ Ckv,
                                                            int K) {
    int bid = blockIdx.x;
    int orig = (bid & 7) * 60 + (bid >> 3);  // XCD-chunked, bijective for 480 blocks
    int by = orig / 15, bx = orig % 15;
    bool isq = bx < 12;
    const bf16* Bm = isq ? Bq : Bkv;
    int n0 = isq ? bx * 128 : (bx - 12) * 128;
    int m0 = by * 128;
    __shared__ bf16 Asf[128 * 32];
    __shared__ bf16 Bsf[128 * 32];
    int tid = threadIdx.x;
    int lane = tid & 63, w = tid >> 6;
    int q4 = lane >> 4, c16 = lane & 15;
    int wr = w >> 1, wc = w & 1;
    floatx4 acc[4][4];
#pragma unroll
    for (int mi = 0; mi < 4; ++mi)
#pragma unroll
        for (int ni = 0; ni < 4; ++ni) acc[mi][ni] = (floatx4){0.f, 0.f, 0.f, 0.f};

    for (int k0 = 0; k0 < K; k0 += 32) {
        __syncthreads();
#pragma unroll
        for (int i = 0; i < 2; ++i) {
            int c = (w << 6) + lane + i * 256;
            int row = c >> 2, kc = c & 3;
            g2l16(&A[(size_t)(m0 + row) * K + k0 + kc * 8], &Asf[c * 8]);
            g2l16(&Bm[(size_t)(n0 + row) * K + k0 + kc * 8], &Bsf[c * 8]);
        }
        __syncthreads();
        short8 af[4], bfr[4];
#pragma unroll
        for (int mi = 0; mi < 4; ++mi)
            af[mi] = *(const short8*)(const void*)&Asf[(wr * 64 + mi * 16 + c16) * 32 + q4 * 8];
#pragma unroll
        for (int ni = 0; ni < 4; ++ni)
            bfr[ni] = *(const short8*)(const void*)&Bsf[(wc * 64 + ni * 16 + c16) * 32 + q4 * 8];
#pragma unroll
        for (int mi = 0; mi < 4; ++mi)
#pragma unroll
            for (int ni = 0; ni < 4; ++ni)
                acc[mi][ni] = __builtin_amdgcn_mfma_f32_16x16x32_bf16(af[mi], bfr[ni], acc[mi][ni], 0, 0, 0);
    }
#pragma unroll
    for (int mi = 0; mi < 4; ++mi)
#pragma unroll
        for (int ni = 0; ni < 4; ++ni)
#pragma unroll
            for (int r = 0; r < 4; ++r) {
                int row = m0 + wr * 64 + mi * 16 + q4 * 4 + r;
                int col = n0 + wc * 64 + ni * 16 + c16;
                if (isq)
                    Cq[(size_t)row * 1536 + col] = __float2bfloat16(acc[mi][ni][r]);
                else
                    Ckv[(size_t)row * 384 + col] = acc[mi][ni][r];
            }
}

// ---------------- small batched bf16 MFMA GEMM (64x64 tiles, global_load_lds) -------------
template <typename TC>
__global__ __launch_bounds__(256, 4) void gemm64_lds(const bf16* __restrict__ A, int lda, int aoffz,
                                                     const bf16* __restrict__ Bm, int ldb, int boffz,
                                                     TC* __restrict__ C, int ldc, int coffz,
                                                     int K, float scale) {
    int z = blockIdx.z;
    A += (size_t)z * aoffz;
    Bm += (size_t)z * boffz;
    C += (size_t)z * coffz;
    __shared__ bf16 Asf[64 * 32];
    __shared__ bf16 Bsf[64 * 32];
    int tid = threadIdx.x;
    int lane = tid & 63, w = tid >> 6;
    int q4 = lane >> 4, c16 = lane & 15;
    int m0 = blockIdx.y * 64, n0 = blockIdx.x * 64;
    floatx4 acc[4];
#pragma unroll
    for (int ni = 0; ni < 4; ++ni) acc[ni] = (floatx4){0.f, 0.f, 0.f, 0.f};
    int row = tid >> 2, kc = tid & 3;
    for (int k0 = 0; k0 < K; k0 += 32) {
        __syncthreads();
        g2l16(&A[(size_t)(m0 + row) * lda + k0 + kc * 8], &Asf[tid * 8]);
        g2l16(&Bm[(size_t)(n0 + row) * ldb + k0 + kc * 8], &Bsf[tid * 8]);
        __syncthreads();
        short8 af = *(const short8*)(const void*)&Asf[(w * 16 + c16) * 32 + q4 * 8];
#pragma unroll
        for (int ni = 0; ni < 4; ++ni) {
            short8 bfr = *(const short8*)(const void*)&Bsf[(ni * 16 + c16) * 32 + q4 * 8];
            acc[ni] = __builtin_amdgcn_mfma_f32_16x16x32_bf16(af, bfr, acc[ni], 0, 0, 0);
        }
    }
#pragma unroll
    for (int ni = 0; ni < 4; ++ni)
#pragma unroll
        for (int rr = 0; rr < 4; ++rr)
            store_c(C, (size_t)(m0 + w * 16 + q4 * 4 + rr) * ldc + n0 + ni * 16 + c16,
                    acc[ni][rr] * scale);
}

// ---------------- qe GEMM specialized: K=64 in ONE phase (2 K-planes staged at once) -----
__global__ __launch_bounds__(256, 4) void gemm_qe_k64(const bf16* __restrict__ A,
                                                      const bf16* __restrict__ Bm,
                                                      bf16* __restrict__ C) {
    int z = blockIdx.z;
    A += (size_t)z * QKD_;
    Bm += (size_t)z * 256 * 64;
    C += (size_t)z * 288;
    __shared__ bf16 Asf[2][64][32];
    __shared__ bf16 Bsf[2][64][32];
    int tid = threadIdx.x;
    int lane = tid & 63, w = tid >> 6;
    int q4 = lane >> 4, c16 = lane & 15;
    int m0 = blockIdx.y * 64, n0 = blockIdx.x * 64;
#pragma unroll
    for (int i = 0; i < 2; ++i) {
        int c = tid + i * 256;           // 512 chunks each; LDS addr = c*16B (linear)
        int pl = c >> 8, r = (c >> 2) & 63, kc = c & 3;
        g2l16(&A[(size_t)(m0 + r) * (H_ * QKD_) + pl * 32 + kc * 8], &Asf[pl][r][kc * 8]);
        g2l16(&Bm[(size_t)(n0 + r) * 64 + pl * 32 + kc * 8], &Bsf[pl][r][kc * 8]);
    }
    __syncthreads();
    floatx4 acc[4];
#pragma unroll
    for (int ni = 0; ni < 4; ++ni) acc[ni] = (floatx4){0.f, 0.f, 0.f, 0.f};
#pragma unroll
    for (int kk = 0; kk < 2; ++kk) {
        short8 af = *(const short8*)(const void*)&Asf[kk][w * 16 + c16][q4 * 8];
#pragma unroll
        for (int ni = 0; ni < 4; ++ni) {
            short8 bfr = *(const short8*)(const void*)&Bsf[kk][ni * 16 + c16][q4 * 8];
            acc[ni] = __builtin_amdgcn_mfma_f32_16x16x32_bf16(af, bfr, acc[ni], 0, 0, 0);
        }
    }
#pragma unroll
    for (int ni = 0; ni < 4; ++ni)
#pragma unroll
        for (int rr = 0; rr < 4; ++rr)
            C[(size_t)(m0 + w * 16 + q4 * 4 + rr) * (H_ * 288) + n0 + ni * 16 + c16] =
                __float2bfloat16(acc[ni][rr] * SCALE_);
}

// ---------------- fused C2/P2 + gates: writes g0/g1 only ----------------
__global__ __launch_bounds__(64) void c2p2g_kernel(const float* __restrict__ fcw_c,
                                                   const float* __restrict__ fcb_c,
                                                   const float* __restrict__ fcw_p,
                                                   const float* __restrict__ fcb_p,
                                                   float* __restrict__ g0,
                                                   float* __restrict__ g1) {
    int t = blockIdx.x;
    int k = threadIdx.x;
    __shared__ float Crow[256], Prow[256], Pprev[256];
    for (int i = k; i < 128; i += 64) {
        float div = expf(-(float)i * 0.07195578415606393f);  // ln(1e4)/128
        float ap = (float)t * div;
        Prow[2 * i]     = sinf(ap);
        Prow[2 * i + 1] = cosf(ap);
        float ac = (float)(t >> 1) * div;
        Crow[2 * i]     = sinf(ac);
        Crow[2 * i + 1] = cosf(ac);
        float app = (float)(t - 1) * div;  // unused for even t
        Pprev[2 * i]     = sinf(app);
        Pprev[2 * i + 1] = cosf(app);
    }
    __syncthreads();
    float sc = fcb_c[k], sp = fcb_p[k], spp = fcb_p[k];
    const float4* wc4 = (const float4*)&fcw_c[(size_t)k * 256];
    const float4* wp4 = (const float4*)&fcw_p[(size_t)k * 256];
#pragma unroll 4
    for (int c4 = 0; c4 < 64; ++c4) {
        float4 wcv = wc4[c4];
        float4 wpv = wp4[c4];
        int c = c4 * 4;
        sc  += Crow[c] * wcv.x + Crow[c + 1] * wcv.y + Crow[c + 2] * wcv.z + Crow[c + 3] * wcv.w;
        sp  += Prow[c] * wpv.x + Prow[c + 1] * wpv.y + Prow[c + 2] * wpv.z + Prow[c + 3] * wpv.w;
        spp += Pprev[c] * wpv.x + Pprev[c + 1] * wpv.y + Pprev[c + 2] * wpv.z + Pprev[c + 3] * wpv.w;
    }
    float d0 = sc * sp, d1 = sc * spp;
#pragma unroll
    for (int o = 32; o; o >>= 1) {
        d0 += __shfl_down(d0, o);
        d1 += __shfl_down(d1, o);
    }
    if (k == 0) {
        g0[t] = 1.0f / (1.0f + expf(-d0));
        g1[t] = (t & 1) ? 1.0f / (1.0f + expf(-d1)) : 0.f;
    }
}

// ---------------- fused LayerNorm + RoPE + gated kve (odd/even pair per block) -----------
__global__ __launch_bounds__(256) void lnkve_kernel(const float* __restrict__ kvraw,
                                                    const float* __restrict__ g,
                                                    const float* __restrict__ bta,
                                                    const float* __restrict__ g0,
                                                    const float* __restrict__ g1,
                                                    bf16* __restrict__ kve_full,
                                                    bf16* __restrict__ kvo) {
    int pb = blockIdx.x;
    int b = pb >> 10, u = pb & 1023;
    int t0 = 2 * u, t1 = 2 * u + 1;
    size_t r0 = (size_t)b * S_ + t0, r1 = r0 + 1;
    int tid = threadIdx.x;
    int lane = tid & 63, w = tid >> 6;
    float x0 = kvraw[r0 * 384 + tid];
    float x1 = kvraw[r1 * 384 + tid];
    float s0 = x0, q0 = x0 * x0, s1 = x1, q1 = x1 * x1;
#pragma unroll
    for (int o = 32; o; o >>= 1) {
        s0 += __shfl_down(s0, o); q0 += __shfl_down(q0, o);
        s1 += __shfl_down(s1, o); q1 += __shfl_down(q1, o);
    }
    __shared__ float red[4][4];
    __shared__ float st[4];
    if (lane == 0) { red[w][0] = s0; red[w][1] = q0; red[w][2] = s1; red[w][3] = q1; }
    __syncthreads();
    if (tid == 0) {
        float S0 = red[0][0] + red[1][0] + red[2][0] + red[3][0];
        float Q0 = red[0][1] + red[1][1] + red[2][1] + red[3][1];
        float S1 = red[0][2] + red[1][2] + red[2][2] + red[3][2];
        float Q1 = red[0][3] + red[1][3] + red[2][3] + red[3][3];
        float m0 = S0 / 256.0f, m1 = S1 / 256.0f;
        st[0] = m0; st[1] = rsqrtf(Q0 / 256.0f - m0 * m0 + 1e-5f);
        st[2] = m1; st[3] = rsqrtf(Q1 / 256.0f - m1 * m1 + 1e-5f);
    }
    __syncthreads();
    float gg = g[tid], bb_ = bta[tid];
    float y0 = (x0 - st[0]) * st[1] * gg + bb_;
    float y1 = (x1 - st[2]) * st[3] * gg + bb_;
    float a0 = g0[t0], a1 = g0[t1], b1 = g1[t1];
    kve_full[r0 * 288 + tid] = __float2bfloat16(a0 * y0);
    float vo = a1 * y1 + b1 * y0;
    bf16 vob = __float2bfloat16(vo);
    kve_full[r1 * 288 + tid] = vob;
    kvo[((size_t)b * 1024 + u) * 296 + tid] = vob;
    if (tid < 16) {
        int j = tid;
        float freq = expf(-(float)(2 * j) * 0.28782313662425572f);  // ln(1e4)/32
        float a00 = (float)t0 * freq, a01 = (float)t1 * freq;
        float c0 = cosf(a00), sn0 = sinf(a00);
        float c1 = cosf(a01), sn1 = sinf(a01);
        float e00 = kvraw[r0 * 384 + 256 + 2 * j], e01 = kvraw[r0 * 384 + 256 + 2 * j + 1];
        float e10 = kvraw[r1 * 384 + 256 + 2 * j], e11 = kvraw[r1 * 384 + 256 + 2 * j + 1];
        float k00 = e00 * c0 - e01 * sn0, k01 = e00 * sn0 + e01 * c0;
        float k10 = e10 * c1 - e11 * sn1, k11 = e10 * sn1 + e11 * c1;
        kve_full[r0 * 288 + 256 + 2 * j]     = __float2bfloat16(a0 * k00);
        kve_full[r0 * 288 + 256 + 2 * j + 1] = __float2bfloat16(a0 * k01);
        float u0 = a1 * k10 + b1 * k00, u1 = a1 * k11 + b1 * k01;
        bf16 u0b = __float2bfloat16(u0), u1b = __float2bfloat16(u1);
        kve_full[r1 * 288 + 256 + 2 * j]     = u0b;
        kve_full[r1 * 288 + 256 + 2 * j + 1] = u1b;
        kvo[((size_t)b * 1024 + u) * 296 + 256 + 2 * j]     = u0b;
        kvo[((size_t)b * 1024 + u) * 296 + 256 + 2 * j + 1] = u1b;
    }
}

// ---------------- kvoT32[b][uch][c][chunk] = kvo[b][uch*32 + tau(kslot)][c] --------------
// tau(8q+j) = (j<4) ? 4q+j : 16 + 4q + (j-4); chunks XOR-swizzled (chunk^((c>>1)&3)) so
// linear global_load_lds staging lands conflict-free (HW-verified R4/R5).
__global__ __launch_bounds__(256) void kvoT32_kernel(const bf16* __restrict__ kvo,
                                                     bf16* __restrict__ kvoT) {
    int uch = blockIdx.x, b = blockIdx.y;
    int c = threadIdx.x;
    const bf16* src = kvo + ((size_t)b * 1024 + uch * 32) * 296 + c;
    short v[32];
#pragma unroll
    for (int j = 0; j < 32; ++j) v[j] = *(const short*)&src[(size_t)j * 296];
    bf16* dst = kvoT + (((size_t)b * 32 + uch) * 256 + c) * 32;
    int swz = (c >> 1) & 3;
#pragma unroll
    for (int q = 0; q < 4; ++q) {
        short8 o;
#pragma unroll
        for (int jj = 0; jj < 8; ++jj)
            o[jj] = (jj < 4) ? v[4 * q + jj] : v[16 + 4 * q + (jj - 4)];
        *(short8*)(void*)&dst[(q ^ swz) * 8] = o;
    }
}

// ---------------- roped, scaled q_pe -> qe[...,256:288) ----------------
__global__ __launch_bounds__(256) void rope_qe_kernel(const bf16* __restrict__ q,
                                                      bf16* __restrict__ qe) {
    int idx = blockIdx.x * 256 + threadIdx.x;
    if (idx >= B_ * S_ * H_ * 16) return;
    int j = idx & 15;
    int s = (idx >> 8) & (S_ - 1);
    float freq = expf(-(float)(2 * j) * 0.28782313662425572f);
    float ang = (float)s * freq;
    float c = cosf(ang), sn = sinf(ang);
    size_t row = idx >> 4;
    float a0 = bf2f(q[row * QKD_ + NOPE_ + 2 * j]);
    float a1 = bf2f(q[row * QKD_ + NOPE_ + 2 * j + 1]);
    qe[row * 288 + 256 + 2 * j]     = __float2bfloat16((a0 * c - a1 * sn) * SCALE_);
    qe[row * 288 + 256 + 2 * j + 1] = __float2bfloat16((a0 * sn + a1 * c) * SCALE_);
}

// ---------------- flash attention: 32-key tiles, dbuf, XOR-swizzled PV, fused sscore -----
// (best measured attn structure — frozen)
__global__ __launch_bounds__(256, 2) void attn8_kernel(const bf16* __restrict__ qe,
                                                       const bf16* __restrict__ kvo,
                                                       const bf16* __restrict__ kvoT,
                                                       const bf16* __restrict__ kve_full,
                                                       bf16* __restrict__ xout) {
    int s0 = (int)(gridDim.x - 1 - blockIdx.x) * 4;  // biggest blocks first
    int b = blockIdx.y;
    int tid = threadIdx.x;
    int lane = tid & 63, w = tid >> 6;
    int q4 = lane >> 4, c16 = lane & 15;
    int s = s0 + w;
    int Nodd = (s + 1) >> 1;
    int NoddMax = (s0 + 4) >> 1;
    int niter = (NoddMax + 31) >> 5;

    __shared__ bf16 kvos[2][32][296];   // 2 x 18944 B: score-side K rows
    __shared__ bf16 kvts[2][256][32];   // 2 x 16384 B: PV-side V tile (tau+XOR layout)
    __shared__ bf16 selfr[4][288];      // self-key kv rows, FULL 288 channels

    const bf16* kvob = kvo + (size_t)b * 1024 * 296;
    const bf16* kvoTb = kvoT + (size_t)b * 32 * 8192;

    if (tid < 144) {
        int rr = tid / 36, ch = tid - rr * 36;
        *(short8*)(void*)&selfr[rr][ch * 8] =
            *(const short8*)(const void*)&kve_full[(size_t)(b * S_ + s0 + rr) * 288 + ch * 8];
    }

    short8 qf[9];
    const bf16* qrow = qe + ((size_t)(b * S_ + s) * H_ + c16) * 288;
#pragma unroll
    for (int kk = 0; kk < 9; ++kk) qf[kk] = *(const short8*)(const void*)&qrow[kk * 32 + q4 * 8];

    floatx4 acc[16];
#pragma unroll
    for (int n = 0; n < 16; ++n) acc[n] = (floatx4){0.f, 0.f, 0.f, 0.f};
    float m_i = -1e30f, l_i = 0.f;
    int swz = (c16 >> 1) & 3;  // PV chunk XOR (matches kvoT32 writer)

    auto stage = [&](int t, int p) {
        const bf16* sa = kvob + (size_t)t * 32 * 296;
        bf16* la = &kvos[p][0][0];
#pragma unroll
        for (int i = 0; i < 4; ++i)
            g2l16(&sa[(size_t)(tid + i * 256) * 8], &la[(size_t)(tid + i * 256) * 8]);
        if (tid < 160) g2l16(&sa[(size_t)(tid + 1024) * 8], &la[(size_t)(tid + 1024) * 8]);
        const bf16* sb = kvoTb + (size_t)t * 8192;
        bf16* lb = &kvts[p][0][0];
#pragma unroll
        for (int i = 0; i < 4; ++i)
            g2l16(&sb[(size_t)(tid + i * 256) * 8], &lb[(size_t)(tid + i * 256) * 8]);
    };

    stage(0, 0);
    __syncthreads();  // prologue drain (also makes selfr visible)

    // in-register self score: dot(qe_row(s,h=c16), kve_row(s)); reduce over q4 via shfl.
    float sdot = 0.f;
#pragma unroll
    for (int kk = 0; kk < 9; ++kk) {
        short8 kv8 = *(const short8*)(const void*)&selfr[w][kk * 32 + q4 * 8];
#pragma unroll
        for (int j = 0; j < 8; ++j) sdot += s2f(qf[kk][j]) * s2f(kv8[j]);
    }
    sdot += __shfl_xor(sdot, 16);
    sdot += __shfl_xor(sdot, 32);

    for (int it = 0; it < niter; ++it) {
        int p = it & 1;
        if (it + 1 < niter) stage(it + 1, 1 - p);

        int u0 = it * 32;
        floatx4 ca0 = (floatx4){0.f, 0.f, 0.f, 0.f}, ca1 = (floatx4){0.f, 0.f, 0.f, 0.f};
        floatx4 cb0 = (floatx4){0.f, 0.f, 0.f, 0.f}, cb1 = (floatx4){0.f, 0.f, 0.f, 0.f};
        __builtin_amdgcn_s_setprio(1);
#pragma unroll
        for (int kk = 0; kk < 9; ++kk) {
            short8 avA = *(const short8*)(const void*)&kvos[p][c16][kk * 32 + q4 * 8];
            short8 avB = *(const short8*)(const void*)&kvos[p][16 + c16][kk * 32 + q4 * 8];
            if (kk & 1) {
                ca1 = __builtin_amdgcn_mfma_f32_16x16x32_bf16(avA, qf[kk], ca1, 0, 0, 0);
                cb1 = __builtin_amdgcn_mfma_f32_16x16x32_bf16(avB, qf[kk], cb1, 0, 0, 0);
            } else {
                ca0 = __builtin_amdgcn_mfma_f32_16x16x32_bf16(avA, qf[kk], ca0, 0, 0, 0);
                cb0 = __builtin_amdgcn_mfma_f32_16x16x32_bf16(avB, qf[kk], cb0, 0, 0, 0);
            }
        }
        __builtin_amdgcn_s_setprio(0);
        floatx4 cA = ca0 + ca1;
        floatx4 cB = cb0 + cb1;
        int kA = u0 + q4 * 4;
        int kB = u0 + 16 + q4 * 4;
#pragma unroll
        for (int r = 0; r < 4; ++r) {
            if (kA + r >= Nodd) cA[r] = -1e30f;
            if (kB + r >= Nodd) cB[r] = -1e30f;
        }
        float tmax = fmaxf(fmaxf(fmaxf(cA[0], cA[1]), fmaxf(cA[2], cA[3])),
                           fmaxf(fmaxf(cB[0], cB[1]), fmaxf(cB[2], cB[3])));
        tmax = fmaxf(tmax, __shfl_xor(tmax, 16));
        tmax = fmaxf(tmax, __shfl_xor(tmax, 32));
        float mn = fmaxf(m_i, tmax);
        bool chg = mn > m_i;
        float al = __expf(m_i - mn);
        float pA0 = __expf(cA[0] - mn), pA1 = __expf(cA[1] - mn);
        float pA2 = __expf(cA[2] - mn), pA3 = __expf(cA[3] - mn);
        float pB0 = __expf(cB[0] - mn), pB1 = __expf(cB[1] - mn);
        float pB2 = __expf(cB[2] - mn), pB3 = __expf(cB[3] - mn);
        float rs = (pA0 + pA1 + pA2 + pA3) + (pB0 + pB1 + pB2 + pB3);
        rs += __shfl_xor(rs, 16);
        rs += __shfl_xor(rs, 32);
        l_i = l_i * al + rs;
        m_i = mn;
        if (__any(chg)) {
#pragma unroll
            for (int n = 0; n < 16; ++n) {
                acc[n][0] *= al; acc[n][1] *= al; acc[n][2] *= al; acc[n][3] *= al;
            }
        }
        short8 pf;
        pf[0] = f2bf_s(pA0); pf[1] = f2bf_s(pA1); pf[2] = f2bf_s(pA2); pf[3] = f2bf_s(pA3);
        pf[4] = f2bf_s(pB0); pf[5] = f2bf_s(pB1); pf[6] = f2bf_s(pB2); pf[7] = f2bf_s(pB3);
        __builtin_amdgcn_s_setprio(1);
#pragma unroll
        for (int n = 0; n < 16; ++n) {
            short8 a8 = *(const short8*)(const void*)&kvts[p][n * 16 + c16][(q4 ^ swz) * 8];
            acc[n] = __builtin_amdgcn_mfma_f32_16x16x32_bf16(a8, pf, acc[n], 0, 0, 0);
        }
        __builtin_amdgcn_s_setprio(0);
        __syncthreads();
    }

    if ((s & 1) == 0) {
        float mn = fmaxf(m_i, sdot);
        float al = __expf(m_i - mn);
        float pp = __expf(sdot - mn);
        l_i = l_i * al + pp;
        m_i = mn;
#pragma unroll
        for (int n = 0; n < 16; ++n) {
            short4v kv4 = *(const short4v*)(const void*)&selfr[w][n * 16 + q4 * 4];
#pragma unroll
            for (int r = 0; r < 4; ++r)
                acc[n][r] = acc[n][r] * al + pp * s2f(kv4[r]);
        }
    }

    float invl = 1.0f / l_i;
    bf16* orow = xout + ((size_t)(b * S_ + s) * H_ + c16) * 256;
#pragma unroll
    for (int n = 0; n < 16; ++n) {
        short4v o;
        o[0] = f2bf_s(acc[n][0] * invl);
        o[1] = f2bf_s(acc[n][1] * invl);
        o[2] = f2bf_s(acc[n][2] * invl);
        o[3] = f2bf_s(acc[n][3] * invl);
        *(short4v*)(void*)&orow[n * 16 + q4 * 4] = o;
    }
}

extern "C" void kernel_launch(void* const* d_in, const int* in_sizes, int n_in,
                              void* d_out, int out_size, void* d_ws, size_t ws_size,
                              hipStream_t stream) {
    const float* hs     = (const float*)d_in[0];
    const float* wq     = (const float*)d_in[1];
    const float* wkv_a  = (const float*)d_in[2];
    const float* ln_g   = (const float*)d_in[3];
    const float* ln_b   = (const float*)d_in[4];
    const float* wkv_b  = (const float*)d_in[5];
    const float* wo     = (const float*)d_in[6];
    const float* fc_c_w = (const float*)d_in[7];
    const float* fc_c_b = (const float*)d_in[8];
    const float* fc_p_w = (const float*)d_in[9];
    const float* fc_p_b = (const float*)d_in[10];
    float* out = (float*)d_out;
    (void)in_sizes; (void)n_in; (void)out_size; (void)ws_size;

    const int M = B_ * S_;  // 4096
    char* wsb = (char*)d_ws;
    size_t o = 0;
    auto alloc = [&](size_t bytes) { char* p = wsb + o; o += (bytes + 255) & ~(size_t)255; return p; };

    bf16* qe = (bf16*)alloc((size_t)M * H_ * 288 * 2);  // 37.75 MB
    char* region2 = alloc((size_t)M * H_ * 256 * 2);    // 33.55 MB
    bf16* hs_bf    = (bf16*)region2;
    bf16* wq_bf    = (bf16*)(region2 + (size_t)M * E_ * 2);
    bf16* wkva_pad = (bf16*)(region2 + (size_t)M * E_ * 2 + (size_t)1536 * E_ * 2);
    bf16* x_bf     = (bf16*)region2;
    char* region3 = alloc((size_t)M * 1536 * 2);        // 12.58 MB
    bf16* q_bf    = (bf16*)region3;
    bf16* outp_bf = (bf16*)region3;
    float* kvraw = (float*)alloc((size_t)M * 384 * 4);
    bf16* wo_bf   = (bf16*)alloc((size_t)E_ * 1024 * 2);
    bf16* wkvb_bf = (bf16*)alloc((size_t)2048 * 256 * 2);
    bf16* wkvbT   = (bf16*)alloc((size_t)H_ * 256 * 64 * 2);
    bf16* kve_full = (bf16*)alloc((size_t)M * 288 * 2);
    bf16* kvo      = (bf16*)alloc((size_t)B_ * 1024 * 296 * 2);
    bf16* kvoT     = (bf16*)alloc((size_t)B_ * 32 * 8192 * 2);
    float* g0 = (float*)alloc(S_ * 4);
    float* g1 = (float*)alloc(S_ * 4);

    // fused conversions + wkvbT transpose — one launch
    conv_fused_kernel<<<(CV_N5 + 255) / 256, 256, 0, stream>>>(
        hs, wq, wo, wkv_b, wkv_a, hs_bf, wq_bf, wo_bf, wkvb_bf, wkva_pad, wkvbT);
    // fused projections: q (bf16) + kvraw (f32), 128x128 tiles, 480 blocks, XCD swizzle
    gemm_qkv_fused128<<<480, 256, 0, stream>>>(hs_bf, wq_bf, wkva_pad, q_bf, kvraw, E_);
    // gates (C2/P2 fused in, float4 weight loads)
    c2p2g_kernel<<<S_, 64, 0, stream>>>(fc_c_w, fc_c_b, fc_p_w, fc_p_b, g0, g1);
    // LN + rope + gated kve (pair-block)
    lnkve_kernel<<<B_ * 1024, 256, 0, stream>>>(kvraw, ln_g, ln_b, g0, g1, kve_full, kvo);
    kvoT32_kernel<<<dim3(32, B_), 256, 0, stream>>>(kvo, kvoT);
    // qe = [q_abs * SCALE | rope(q_pe) * SCALE]  (single-phase K=64 GEMM)
    gemm_qe_k64<<<dim3(4, 64, 16), 256, 0, stream>>>(q_bf, wkvbT, qe);
    rope_qe_kernel<<<(M * H_ * 16 + 255) / 256, 256, 0, stream>>>(q_bf, qe);
    // attention (frozen)
    attn8_kernel<<<dim3(S_ / 4, B_), 256, 0, stream>>>(qe, kvo, kvoT, kve_full, x_bf);
    // V-projection per head
    gemm64_lds<bf16><<<dim3(1, M / 64, H_), 256, 0, stream>>>(
        x_bf, H_ * 256, 256, wkvb_bf + (size_t)64 * 256, 256, 128 * 256, outp_bf, 1024, 64, 256, 1.0f);
    // final out = outp @ wo^T
    gemm_bt_lds<float><<<dim3(E_ / 128, M / 128), 256, 0, stream>>>(outp_bf, wo_bf, out, M, E_, 1024);
}